// Round 10
// baseline (123.680 us; speedup 1.0000x reference)
//
#include <hip/hip_runtime.h>
#include <cstdint>
#include <cstddef>

using short8 = __attribute__((ext_vector_type(8))) short;
using f32x4  = __attribute__((ext_vector_type(4))) float;
using bfraw  = unsigned short;

// ---------------- helpers ----------------
__device__ __forceinline__ bfraw f2b(float f){
  unsigned int u = __builtin_bit_cast(unsigned int, f);
  u += 0x7FFFu + ((u >> 16) & 1u);            // round-to-nearest-even
  return (bfraw)(u >> 16);
}
__device__ __forceinline__ float b2f(bfraw h){
  unsigned int u = ((unsigned int)h) << 16;
  return __builtin_bit_cast(float, u);
}
__device__ __forceinline__ float srelu(float x){ // smooth_relu, d=0.1
  float r = fmaxf(x, 0.0f);
  if (r < 0.1f){ float r2 = r * r; return (0.2f * r2 * r - r2 * r2) * 500.0f; }
  return x - 0.05f;
}
__device__ __forceinline__ float softplusf(float x){
  return (x > 15.0f) ? x : log1pf(expf(x));
}
__device__ __forceinline__ void gload16(const void* g, void* s){
  __builtin_amdgcn_global_load_lds((const __attribute__((address_space(1))) void*)g,
                                   (__attribute__((address_space(3))) void*)s, 16, 0, 0);
}
// counted vmcnt wait (T4): wait until <= N vmem ops outstanding (per-wave FIFO)
template<int N> __device__ __forceinline__ void wait_vm(){
  if constexpr (N == 0)      asm volatile("s_waitcnt vmcnt(0)" ::: "memory");
  else if constexpr (N == 2) asm volatile("s_waitcnt vmcnt(2)" ::: "memory");
  else if constexpr (N == 3) asm volatile("s_waitcnt vmcnt(3)" ::: "memory");
  else                       asm volatile("s_waitcnt vmcnt(4)" ::: "memory");
}
__device__ __forceinline__ void block_barrier(){
  __builtin_amdgcn_s_barrier();
  asm volatile("" ::: "memory");   // no memory op crosses the barrier upward
}

// ---------------- workspace layout (bytes) ----------------
constexpr size_t OFF_STATEB = 0;               // 4096*2048 bf16 = 16MB
constexpr size_t OFF_HUB    = 16777216;        // 4096*1024 bf16 = 8MB
constexpr size_t OFF_PT     = 27262976;        // 1024*1024 bf16 (P^T)
constexpr size_t OFF_PTEIG  = 29360128;        // 1024*1024 bf16 ((eig*P)^T)
constexpr size_t OFF_LM     = 31457280;        // 1024*1024 bf16 (Lm)
constexpr size_t OFF_W1ZB   = 37748736;        // 640*2048 bf16 (W1‖icW0‖icW1)
constexpr size_t OFF_W2B    = 40370176;        // 512*512 bf16
constexpr size_t OFF_W3B    = 40894464;        // 2048*512 bf16
constexpr size_t OFF_H1B    = 42991616;        // 4096*512 bf16
constexpr size_t OFF_H2B    = 47185920;        // 4096*512 bf16
constexpr size_t OFF_Z1F    = 51380224;        // 4096*64 f32
constexpr size_t OFF_Z2PRE  = 52428800;        // 4096*64 f32
constexpr size_t OFF_SPU0   = 54525952;        // 64*64 f32
constexpr size_t OFF_SPU1   = 54542336;        // 64 f32
constexpr size_t OFF_Z0     = 54542592;        // 1 f32 (padded)
constexpr size_t OFF_SU1    = 54542848;        // 512 f32
constexpr size_t OFF_SV1    = 54544896;        // 512 f32
constexpr size_t OFF_U0     = 54546944;        // 4096 f32
constexpr size_t OFF_V0     = 54563328;        // 4096 f32

// ---------------- fused prep: weights cast | P transpose(+eig) | W1 rowsums | icnn tables ----------------
__global__ __launch_bounds__(256) void prep_fused(const float* __restrict__ W1,
    const float* __restrict__ icW0, const float* __restrict__ icW1,
    const float* __restrict__ W2, const float* __restrict__ W3,
    const float* __restrict__ P, const float* __restrict__ tptr,
    const float* __restrict__ icU0, const float* __restrict__ icU1,
    const float* __restrict__ icb0, const float* __restrict__ icb1, const float* __restrict__ icb2,
    bfraw* __restrict__ w1zb, bfraw* __restrict__ w2b, bfraw* __restrict__ w3b,
    bfraw* __restrict__ PT, bfraw* __restrict__ PTeig,
    float* __restrict__ su1, float* __restrict__ sv1,
    float* __restrict__ spU0, float* __restrict__ spU1, float* __restrict__ z0out){
  __shared__ float smem[4288];
  const int b = blockIdx.x;
  const int t = threadIdx.x;
  if (b < 2560){
    const int i4 = (b * 256 + t) * 4;
    const float* src; bfraw* dst; int off;
    if (i4 < 1048576)      { src = W1;   dst = w1zb;           off = i4; }
    else if (i4 < 1179648) { src = icW0; dst = w1zb + 1048576; off = i4 - 1048576; }
    else if (i4 < 1310720) { src = icW1; dst = w1zb + 1179648; off = i4 - 1179648; }
    else if (i4 < 1572864) { src = W2;   dst = w2b;            off = i4 - 1310720; }
    else                   { src = W3;   dst = w3b;            off = i4 - 1572864; }
    float4 v = *reinterpret_cast<const float4*>(src + off);
    ushort4 o;
    o.x = f2b(v.x); o.y = f2b(v.y); o.z = f2b(v.z); o.w = f2b(v.w);
    *reinterpret_cast<ushort4*>(dst + off) = o;
  } else if (b < 3584){
    float (*tile)[33] = (float(*)[33])smem;
    const int idx = b - 2560;
    const int bi = idx >> 5, bj = idx & 31;
    const int tx = t & 31, ty = t >> 5;
    #pragma unroll
    for (int r = 0; r < 4; ++r){
      const int k = bj * 32 + ty + r * 8;
      const int i = bi * 32 + tx;
      tile[ty + r * 8][tx] = P[(size_t)k * 1024 + i];
    }
    __syncthreads();
    const float s = 2.0f * sinf(tptr[0]);
    #pragma unroll
    for (int r = 0; r < 4; ++r){
      const int i = bi * 32 + ty + r * 8;
      const int k = bj * 32 + tx;
      const float p = tile[tx][ty + r * 8];
      const float e = (k == 0) ? 0.0f : ((k <= 511) ? (1.0f + s) : (1.0f - s));
      PT[(size_t)i * 1024 + k] = f2b(p);
      PTeig[(size_t)i * 1024 + k] = f2b(e * p);
    }
  } else if (b < 4096){
    const int n = b - 3584;
    float a = 0.0f, bb = 0.0f;
    for (int j = t; j < 1024; j += 256) a += W1[(size_t)n * 2048 + j];
    for (int j = t; j < 1024; j += 256) bb += W1[(size_t)n * 2048 + 1024 + j];
    #pragma unroll
    for (int o = 32; o > 0; o >>= 1){ a += __shfl_down(a, o, 64); bb += __shfl_down(bb, o, 64); }
    if ((t & 63) == 0){ smem[t >> 6] = a; smem[4 + (t >> 6)] = bb; }
    __syncthreads();
    if (t == 0){
      su1[n] = smem[0] + smem[1] + smem[2] + smem[3];
      sv1[n] = smem[4] + smem[5] + smem[6] + smem[7];
    }
  } else {
    float* sp  = smem;          // 4096
    float* sp1 = smem + 4096;   // 64
    float* a0  = smem + 4160;   // 64
    float* a1  = smem + 4224;   // 64
    #pragma unroll
    for (int i = 0; i < 16; ++i){
      const int idx = i * 256 + t;
      const float v = softplusf(icU0[idx]);
      sp[idx] = v;
      spU0[idx] = v;
    }
    if (t < 64){
      const float v1 = softplusf(icU1[t]);
      sp1[t] = v1;
      spU1[t] = v1;
      a0[t] = srelu(icb0[t]);
    }
    __syncthreads();
    {
      const int n = t >> 2, q = t & 3;
      float sAcc = 0.0f;
      #pragma unroll
      for (int j = 0; j < 16; ++j) sAcc += sp[n * 64 + q * 16 + j] * a0[q * 16 + j];
      sAcc += __shfl_down(sAcc, 2, 64);
      sAcc += __shfl_down(sAcc, 1, 64);
      if (q == 0) a1[n] = srelu(sAcc + icb1[n]);
    }
    __syncthreads();
    if (t < 64){
      float v = sp1[t] * a1[t];
      #pragma unroll
      for (int o = 32; o > 0; o >>= 1) v += __shfl_down(v, o, 64);
      if (t == 0) z0out[0] = srelu(v + icb2[0]);
    }
  }
}

// per-row: state->bf16, Hu=sigmoid(u/0.1)->bf16, u0/v0 arrays
__global__ __launch_bounds__(256) void prep_state(const float* __restrict__ state,
    bfraw* __restrict__ stateb, bfraw* __restrict__ hub,
    float* __restrict__ u0a, float* __restrict__ v0a){
  const int row = blockIdx.x;
  const int t = threadIdx.x;
  const float* srow = state + (size_t)row * 2048;
  float4 u4 = *reinterpret_cast<const float4*>(srow + t * 4);
  float4 v4 = *reinterpret_cast<const float4*>(srow + 1024 + t * 4);
  float us[4] = {u4.x, u4.y, u4.z, u4.w};
  float vs[4] = {v4.x, v4.y, v4.z, v4.w};
  #pragma unroll
  for (int i = 0; i < 4; ++i){
    const int j = t * 4 + i;
    const float u = us[i], v = vs[i];
    stateb[(size_t)row * 2048 + j] = f2b(u);
    stateb[(size_t)row * 2048 + 1024 + j] = f2b(v);
    hub[(size_t)row * 1024 + j] = f2b(1.0f / (1.0f + expf(-10.0f * u)));
  }
  if (t == 0){ u0a[row] = srow[0]; v0a[row] = srow[1024]; }
}

// fused z2 + V column; reads bf16 stateb
__global__ __launch_bounds__(256) void v2_kernel(const bfraw* __restrict__ stateb, const float* __restrict__ icW2,
    const float* __restrict__ z1f, const float* __restrict__ z2pre,
    const float* __restrict__ spU0, const float* __restrict__ spU1,
    const float* __restrict__ z0p, const float* __restrict__ icb2, float* __restrict__ out){
  const int row = blockIdx.x;
  const int t = threadIdx.x;
  __shared__ float z1s[64];
  __shared__ float s1[4], s2[4];
  if (t < 64) z1s[t] = z1f[(size_t)row * 64 + t];
  short8 xv = reinterpret_cast<const short8*>(stateb + (size_t)row * 2048)[t];
  float4 w0 = reinterpret_cast<const float4*>(icW2)[t * 2];
  float4 w1 = reinterpret_cast<const float4*>(icW2)[t * 2 + 1];
  float wv[8] = {w0.x, w0.y, w0.z, w0.w, w1.x, w1.y, w1.z, w1.w};
  float d = 0.0f, ss = 0.0f;
  #pragma unroll
  for (int e = 0; e < 8; ++e){
    const float x = b2f((bfraw)xv[e]);
    d  = fmaf(wv[e], x, d);
    ss = fmaf(x, x, ss);
  }
  #pragma unroll
  for (int o = 32; o > 0; o >>= 1){ d += __shfl_down(d, o, 64); ss += __shfl_down(ss, o, 64); }
  if ((t & 63) == 0){ s1[t >> 6] = d; s2[t >> 6] = ss; }
  __syncthreads();
  if (t < 64){
    float acc2 = z2pre[(size_t)row * 64 + t];
    #pragma unroll 8
    for (int j = 0; j < 64; ++j) acc2 += spU0[t * 64 + j] * z1s[j];
    float dd = spU1[t] * srelu(acc2);
    #pragma unroll
    for (int o = 32; o > 0; o >>= 1) dd += __shfl_down(dd, o, 64);
    if (t == 0){
      const float D = dd + s1[0] + s1[1] + s1[2] + s1[3];
      const float S = s2[0] + s2[1] + s2[2] + s2[3];
      const float z3 = srelu(D + icb2[0]);
      out[(size_t)row * 2049 + 2048] = srelu(z3 - z0p[0]) + 0.001f * S;
    }
  }
}

// ---------------- MFMA NT-GEMM: triple-buffered LDS, counted vmcnt, XOR-swizzled (BK=64) ----------------
// EPI: 0 = plain bf16 store (Lm) | 2 = tanh(+bias)->bf16 | 4 = h1/z1/z2 split
template<int EPI, int TM, int TN>
__global__ __launch_bounds__(512)
void gemm_nt(const bfraw* __restrict__ A, const bfraw* __restrict__ B,
             int N, int K,
             const float* __restrict__ bias,
             bfraw* __restrict__ outb,
             const float* __restrict__ u0a, const float* __restrict__ v0a,
             const float* __restrict__ su1, const float* __restrict__ sv1,
             const float* __restrict__ icb0, const float* __restrict__ icb1,
             float* __restrict__ z1f, float* __restrict__ z2pre)
{
  constexpr int MF = TM / 32;
  constexpr int NF = TN / 64;
  constexpr int LPB = TM / 64 + TN / 64;   // gload16 ops per wave per stage
  __shared__ bfraw lA[3][TM * 64];
  __shared__ bfraw lB[3][TN * 64];
  const int tid = threadIdx.x;
  const int w  = tid >> 6;
  const int l  = tid & 63;
  const int wr = w >> 2;
  const int wc = w & 3;
  const int bm = blockIdx.x;
  const int bn = blockIdx.y;
  const int lr = l & 15;
  const int q  = l >> 4;

  f32x4 acc[MF][NF] = {};
  const int nt = K >> 6;

  auto stage = [&](int buf, int k0){
    #pragma unroll
    for (int j = 0; j < TM / 64; ++j){
      const int c = j * 512 + tid;
      const int r = c >> 3;
      const int kc = (c & 7) ^ (r & 7);
      gload16(A + (size_t)(bm * TM + r) * K + k0 + kc * 8, &lA[buf][(size_t)(j * 512 + w * 64) * 8]);
    }
    #pragma unroll
    for (int j = 0; j < TN / 64; ++j){
      const int c = j * 512 + tid;
      const int r = c >> 3;
      const int kc = (c & 7) ^ (r & 7);
      gload16(B + (size_t)(bn * TN + r) * K + k0 + kc * 8, &lB[buf][(size_t)(j * 512 + w * 64) * 8]);
    }
  };

  stage(0, 0);
  stage(1, 64);
  for (int t = 0; t < nt; ++t){
    const int cur = t % 3;
    if (t == nt - 1) wait_vm<0>(); else wait_vm<LPB>();
    block_barrier();
    short8 aF[2][MF], bF[2][NF];
    #pragma unroll
    for (int kh = 0; kh < 2; ++kh){
      #pragma unroll
      for (int m = 0; m < MF; ++m){
        const int R = wr * (TM / 2) + m * 16 + lr;
        const int kch = (kh * 4 + q) ^ (lr & 7);
        aF[kh][m] = *reinterpret_cast<const short8*>(&lA[cur][(size_t)R * 64 + kch * 8]);
      }
      #pragma unroll
      for (int n = 0; n < NF; ++n){
        const int R = wc * (TN / 4) + n * 16 + lr;
        const int kch = (kh * 4 + q) ^ (lr & 7);
        bF[kh][n] = *reinterpret_cast<const short8*>(&lB[cur][(size_t)R * 64 + kch * 8]);
      }
    }
    if (t + 2 < nt) stage((t + 2) % 3, (t + 2) * 64);
    #pragma unroll
    for (int kh = 0; kh < 2; ++kh){
      #pragma unroll
      for (int m = 0; m < MF; ++m){
        #pragma unroll
        for (int n = 0; n < NF; ++n){
          acc[m][n] = __builtin_amdgcn_mfma_f32_16x16x32_bf16(aF[kh][m], bF[kh][n], acc[m][n], 0, 0, 0);
        }
      }
    }
  }

  #pragma unroll
  for (int m = 0; m < MF; ++m){
    #pragma unroll
    for (int n = 0; n < NF; ++n){
      #pragma unroll
      for (int r = 0; r < 4; ++r){
        const int row = bm * TM + wr * (TM / 2) + m * 16 + q * 4 + r;
        const int col = bn * TN + wc * (TN / 4) + n * 16 + lr;
        const float v = acc[m][n][r];
        if constexpr (EPI == 0){
          outb[(size_t)row * N + col] = f2b(v);
        } else if constexpr (EPI == 2){
          outb[(size_t)row * N + col] = f2b(tanhf(v + bias[col]));
        } else if constexpr (EPI == 4){
          if (col < 512){
            const float h = v - u0a[row] * su1[col] - v0a[row] * sv1[col] + bias[col];
            outb[(size_t)row * 512 + col] = f2b(tanhf(h));
          } else if (col < 576){
            z1f[(size_t)row * 64 + (col - 512)] = srelu(v + icb0[col - 512]);
          } else {
            z2pre[(size_t)row * 64 + (col - 576)] = v + icb1[col - 576];
          }
        }
      }
    }
  }
}

// ---------------- dual-K output GEMM, m97-style: 256 thr (2x2 waves), TM=128 TN=64,
// single 24KB LDS buffer, stage->sync->compute->sync; 4 blocks/CU cover the barrier drain.
// Two clean per-phase loops (no per-tile phase branch). Proven BK=64 swizzle.
// out[:, :2048] written ONCE: col<1024: du + u - u^3/3 - v + 1 + clamp(un*st);
//                             col>=1024: 0.2*(u+0.7-0.8*v) + clamp(un*st)
__global__ __launch_bounds__(256)
void gemm_out(const bfraw* __restrict__ hub, const bfraw* __restrict__ lm,
              const bfraw* __restrict__ h2b, const bfraw* __restrict__ w3b,
              const bfraw* __restrict__ stateb, const float* __restrict__ b3,
              const float* __restrict__ u0a, const float* __restrict__ v0a,
              float* __restrict__ out)
{
  __shared__ bfraw lA[128 * 64];   // 16KB
  __shared__ bfraw lB[64 * 64];    // 8KB
  const int tid = threadIdx.x;     // 256
  const int w  = tid >> 6;         // 0..3
  const int l  = tid & 63;
  const int wr = w >> 1;           // 0..1
  const int wc = w & 1;            // 0..1
  const int bm = blockIdx.x;       // 0..31 (row tiles of 128)
  const int bn = blockIdx.y;       // 0..31 (col tiles of 64)
  const int lr = l & 15;
  const int q  = l >> 4;
  const bool hasDu = (bn < 16);

  f32x4 acc1[4][2] = {};           // wave tile 64x32: MF=4, NF=2
  f32x4 acc2[4][2] = {};

  auto run_phase = [&](const bfraw* __restrict__ Ap, const bfraw* __restrict__ Bp,
                       int K, int nt, auto& acc){
    for (int t = 0; t < nt; ++t){
      const int k0 = t * 64;
      #pragma unroll
      for (int j = 0; j < 4; ++j){
        const int c = j * 256 + tid;
        const int r = c >> 3;
        const int kc = (c & 7) ^ (r & 7);
        gload16(Ap + (size_t)(bm * 128 + r) * K + k0 + kc * 8, &lA[(size_t)(j * 256 + w * 64) * 8]);
      }
      #pragma unroll
      for (int j = 0; j < 2; ++j){
        const int c = j * 256 + tid;
        const int r = c >> 3;
        const int kc = (c & 7) ^ (r & 7);
        gload16(Bp + (size_t)(bn * 64 + r) * K + k0 + kc * 8, &lB[(size_t)(j * 256 + w * 64) * 8]);
      }
      __syncthreads();               // drains vmcnt: tile ready
      short8 aF[2][4], bF[2][2];
      #pragma unroll
      for (int kh = 0; kh < 2; ++kh){
        #pragma unroll
        for (int m = 0; m < 4; ++m){
          const int R = wr * 64 + m * 16 + lr;
          const int kch = (kh * 4 + q) ^ (lr & 7);
          aF[kh][m] = *reinterpret_cast<const short8*>(&lA[(size_t)R * 64 + kch * 8]);
        }
        #pragma unroll
        for (int n = 0; n < 2; ++n){
          const int R = wc * 32 + n * 16 + lr;
          const int kch = (kh * 4 + q) ^ (lr & 7);
          bF[kh][n] = *reinterpret_cast<const short8*>(&lB[(size_t)R * 64 + kch * 8]);
        }
      }
      #pragma unroll
      for (int kh = 0; kh < 2; ++kh)
        #pragma unroll
        for (int m = 0; m < 4; ++m)
          #pragma unroll
          for (int n = 0; n < 2; ++n)
            acc[m][n] = __builtin_amdgcn_mfma_f32_16x16x32_bf16(aF[kh][m], bF[kh][n], acc[m][n], 0, 0, 0);
      __syncthreads();               // reads done before next stage overwrites
    }
  };

  if (hasDu) run_phase(hub, lm, 1024, 16, acc1);
  run_phase(h2b, w3b, 512, 8, acc2);

  #pragma unroll
  for (int m = 0; m < 4; ++m){
    #pragma unroll
    for (int n = 0; n < 2; ++n){
      #pragma unroll
      for (int r = 0; r < 4; ++r){
        const int row = bm * 128 + wr * 64 + m * 16 + q * 4 + r;
        const int col = bn * 64 + wc * 32 + n * 16 + lr;
        const float un = acc2[m][n][r] + b3[col];
        float base, x;
        if (hasDu){
          const float u = b2f(stateb[(size_t)row * 2048 + col]);
          const float v = b2f(stateb[(size_t)row * 2048 + 1024 + col]);
          base = acc1[m][n][r] + u - u * u * u * (1.0f / 3.0f) - v + 1.0f;
          x = u - u0a[row];
        } else {
          const float u  = b2f(stateb[(size_t)row * 2048 + col - 1024]);
          const float vv = b2f(stateb[(size_t)row * 2048 + col]);
          base = 0.2f * (u + 0.7f - 0.8f * vv);
          x = vv - v0a[row];
        }
        const float ux = un * x;
        const float c = (ux < 10.0f && -10.0f < ux) ? ux : 0.0f;
        out[(size_t)row * 2049 + col] = base + c;
      }
    }
  }
}

// ---------------- launch ----------------
extern "C" void kernel_launch(void* const* d_in, const int* in_sizes, int n_in,
                              void* d_out, int out_size, void* d_ws, size_t ws_size,
                              hipStream_t stream){
  (void)in_sizes; (void)n_in; (void)out_size; (void)ws_size;
  const float* state = (const float*)d_in[0];
  const float* tp    = (const float*)d_in[1];
  const float* P     = (const float*)d_in[2];
  const float* W1    = (const float*)d_in[3];
  const float* b1    = (const float*)d_in[4];
  const float* W2    = (const float*)d_in[5];
  const float* b2    = (const float*)d_in[6];
  const float* W3    = (const float*)d_in[7];
  const float* b3    = (const float*)d_in[8];
  const float* icW0  = (const float*)d_in[9];
  const float* icb0  = (const float*)d_in[10];
  const float* icW1  = (const float*)d_in[11];
  const float* icb1  = (const float*)d_in[12];
  const float* icW2  = (const float*)d_in[13];
  const float* icb2  = (const float*)d_in[14];
  const float* icU0  = (const float*)d_in[15];
  const float* icU1  = (const float*)d_in[16];
  float* out = (float*)d_out;
  char* ws = (char*)d_ws;

  bfraw* stateb = (bfraw*)(ws + OFF_STATEB);
  bfraw* hub    = (bfraw*)(ws + OFF_HUB);
  bfraw* pt     = (bfraw*)(ws + OFF_PT);
  bfraw* pteig  = (bfraw*)(ws + OFF_PTEIG);
  bfraw* lm     = (bfraw*)(ws + OFF_LM);
  bfraw* w1zb   = (bfraw*)(ws + OFF_W1ZB);
  bfraw* w2b    = (bfraw*)(ws + OFF_W2B);
  bfraw* w3b    = (bfraw*)(ws + OFF_W3B);
  bfraw* h1b    = (bfraw*)(ws + OFF_H1B);
  bfraw* h2b    = (bfraw*)(ws + OFF_H2B);
  float* z1f    = (float*)(ws + OFF_Z1F);
  float* z2pre  = (float*)(ws + OFF_Z2PRE);
  float* spU0   = (float*)(ws + OFF_SPU0);
  float* spU1   = (float*)(ws + OFF_SPU1);
  float* z0     = (float*)(ws + OFF_Z0);
  float* su1    = (float*)(ws + OFF_SU1);
  float* sv1    = (float*)(ws + OFF_SV1);
  float* u0a    = (float*)(ws + OFF_U0);
  float* v0a    = (float*)(ws + OFF_V0);

  prep_fused<<<dim3(4097), 256, 0, stream>>>(W1, icW0, icW1, W2, W3, P, tp,
      icU0, icU1, icb0, icb1, icb2,
      w1zb, w2b, w3b, pt, pteig, su1, sv1, spU0, spU1, z0);
  prep_state<<<dim3(4096), 256, 0, stream>>>(state, stateb, hub, u0a, v0a);

  // Lm = (eig*P)^T @ P   (1024x1024, K=1024) -> bf16
  gemm_nt<0, 64, 64><<<dim3(16, 16), 512, 0, stream>>>(pteig, pt, 1024, 1024,
      nullptr, lm, nullptr, nullptr, nullptr, nullptr, nullptr, nullptr, nullptr, nullptr);
  // h1 = tanh(state@W1^T - u0*su1 - v0*sv1 + b1) ; z1 ; z2pre   (4096x640, K=2048)
  gemm_nt<4, 64, 128><<<dim3(64, 5), 512, 0, stream>>>(stateb, w1zb, 640, 2048,
      b1, h1b, u0a, v0a, su1, sv1, icb0, icb1, z1f, z2pre);
  // h2 = tanh(h1 @ W2^T + b2)   (4096x512, K=512)
  gemm_nt<2, 64, 128><<<dim3(64, 4), 512, 0, stream>>>(h1b, w2b, 512, 512,
      b2, h2b, nullptr, nullptr, nullptr, nullptr, nullptr, nullptr, nullptr, nullptr);
  // out[:, :2048] = dx + ctrl  (dual-K fused GEMM, 4096x2048, m97-style)
  gemm_out<<<dim3(32, 32), 256, 0, stream>>>(hub, lm, h2b, w3b, stateb, b3, u0a, v0a, out);

  v2_kernel<<<dim3(4096), 256, 0, stream>>>(stateb, icW2, z1f, z2pre, spU0, spU1, z0, icb2, out);
}

// Round 11
// 110.193 us; speedup vs baseline: 1.1224x; 1.1224x over previous
//
#include <hip/hip_runtime.h>
#include <cstdint>
#include <cstddef>

using short8 = __attribute__((ext_vector_type(8))) short;
using f32x4  = __attribute__((ext_vector_type(4))) float;
using bfraw  = unsigned short;

// ---------------- helpers ----------------
__device__ __forceinline__ bfraw f2b(float f){
  unsigned int u = __builtin_bit_cast(unsigned int, f);
  u += 0x7FFFu + ((u >> 16) & 1u);            // round-to-nearest-even
  return (bfraw)(u >> 16);
}
__device__ __forceinline__ float b2f(bfraw h){
  unsigned int u = ((unsigned int)h) << 16;
  return __builtin_bit_cast(float, u);
}
__device__ __forceinline__ float srelu(float x){ // smooth_relu, d=0.1
  float r = fmaxf(x, 0.0f);
  if (r < 0.1f){ float r2 = r * r; return (0.2f * r2 * r - r2 * r2) * 500.0f; }
  return x - 0.05f;
}
__device__ __forceinline__ float softplusf(float x){
  return (x > 15.0f) ? x : log1pf(expf(x));
}
__device__ __forceinline__ void gload16(const void* g, void* s){
  __builtin_amdgcn_global_load_lds((const __attribute__((address_space(1))) void*)g,
                                   (__attribute__((address_space(3))) void*)s, 16, 0, 0);
}
// counted vmcnt wait (T4): wait until <= N vmem ops outstanding (per-wave FIFO)
template<int N> __device__ __forceinline__ void wait_vm(){
  if constexpr (N == 0)      asm volatile("s_waitcnt vmcnt(0)" ::: "memory");
  else if constexpr (N == 2) asm volatile("s_waitcnt vmcnt(2)" ::: "memory");
  else if constexpr (N == 3) asm volatile("s_waitcnt vmcnt(3)" ::: "memory");
  else                       asm volatile("s_waitcnt vmcnt(4)" ::: "memory");
}
__device__ __forceinline__ void block_barrier(){
  __builtin_amdgcn_s_barrier();
  asm volatile("" ::: "memory");   // no memory op crosses the barrier upward
}

// ---------------- workspace layout (bytes) ----------------
constexpr size_t OFF_STATEB = 0;               // 4096*2048 bf16 = 16MB
constexpr size_t OFF_HUB    = 16777216;        // 4096*1024 bf16 = 8MB
constexpr size_t OFF_PT     = 27262976;        // 1024*1024 bf16 (P^T)
constexpr size_t OFF_PTEIG  = 29360128;        // 1024*1024 bf16 ((eig*P)^T)
constexpr size_t OFF_LM     = 31457280;        // 1024*1024 bf16 (Lm)
constexpr size_t OFF_W1ZB   = 37748736;        // 640*2048 bf16 (W1‖icW0‖icW1)
constexpr size_t OFF_W2B    = 40370176;        // 512*512 bf16
constexpr size_t OFF_W3B    = 40894464;        // 2048*512 bf16
constexpr size_t OFF_H1B    = 42991616;        // 4096*512 bf16
constexpr size_t OFF_H2B    = 47185920;        // 4096*512 bf16
constexpr size_t OFF_Z1F    = 51380224;        // 4096*64 f32
constexpr size_t OFF_Z2PRE  = 52428800;        // 4096*64 f32
constexpr size_t OFF_SPU0   = 54525952;        // 64*64 f32
constexpr size_t OFF_SPU1   = 54542336;        // 64 f32
constexpr size_t OFF_Z0     = 54542592;        // 1 f32 (padded)
constexpr size_t OFF_SU1    = 54542848;        // 512 f32
constexpr size_t OFF_SV1    = 54544896;        // 512 f32
constexpr size_t OFF_U0     = 54546944;        // 4096 f32
constexpr size_t OFF_V0     = 54563328;        // 4096 f32

// ---------------- fused prep: weights cast | P transpose(+eig) | W1 rowsums | icnn tables ----------------
__global__ __launch_bounds__(256) void prep_fused(const float* __restrict__ W1,
    const float* __restrict__ icW0, const float* __restrict__ icW1,
    const float* __restrict__ W2, const float* __restrict__ W3,
    const float* __restrict__ P, const float* __restrict__ tptr,
    const float* __restrict__ icU0, const float* __restrict__ icU1,
    const float* __restrict__ icb0, const float* __restrict__ icb1, const float* __restrict__ icb2,
    bfraw* __restrict__ w1zb, bfraw* __restrict__ w2b, bfraw* __restrict__ w3b,
    bfraw* __restrict__ PT, bfraw* __restrict__ PTeig,
    float* __restrict__ su1, float* __restrict__ sv1,
    float* __restrict__ spU0, float* __restrict__ spU1, float* __restrict__ z0out){
  __shared__ float smem[4288];
  const int b = blockIdx.x;
  const int t = threadIdx.x;
  if (b < 2560){
    const int i4 = (b * 256 + t) * 4;
    const float* src; bfraw* dst; int off;
    if (i4 < 1048576)      { src = W1;   dst = w1zb;           off = i4; }
    else if (i4 < 1179648) { src = icW0; dst = w1zb + 1048576; off = i4 - 1048576; }
    else if (i4 < 1310720) { src = icW1; dst = w1zb + 1179648; off = i4 - 1179648; }
    else if (i4 < 1572864) { src = W2;   dst = w2b;            off = i4 - 1310720; }
    else                   { src = W3;   dst = w3b;            off = i4 - 1572864; }
    float4 v = *reinterpret_cast<const float4*>(src + off);
    ushort4 o;
    o.x = f2b(v.x); o.y = f2b(v.y); o.z = f2b(v.z); o.w = f2b(v.w);
    *reinterpret_cast<ushort4*>(dst + off) = o;
  } else if (b < 3584){
    float (*tile)[33] = (float(*)[33])smem;
    const int idx = b - 2560;
    const int bi = idx >> 5, bj = idx & 31;
    const int tx = t & 31, ty = t >> 5;
    #pragma unroll
    for (int r = 0; r < 4; ++r){
      const int k = bj * 32 + ty + r * 8;
      const int i = bi * 32 + tx;
      tile[ty + r * 8][tx] = P[(size_t)k * 1024 + i];
    }
    __syncthreads();
    const float s = 2.0f * sinf(tptr[0]);
    #pragma unroll
    for (int r = 0; r < 4; ++r){
      const int i = bi * 32 + ty + r * 8;
      const int k = bj * 32 + tx;
      const float p = tile[tx][ty + r * 8];
      const float e = (k == 0) ? 0.0f : ((k <= 511) ? (1.0f + s) : (1.0f - s));
      PT[(size_t)i * 1024 + k] = f2b(p);
      PTeig[(size_t)i * 1024 + k] = f2b(e * p);
    }
  } else if (b < 4096){
    const int n = b - 3584;
    float a = 0.0f, bb = 0.0f;
    for (int j = t; j < 1024; j += 256) a += W1[(size_t)n * 2048 + j];
    for (int j = t; j < 1024; j += 256) bb += W1[(size_t)n * 2048 + 1024 + j];
    #pragma unroll
    for (int o = 32; o > 0; o >>= 1){ a += __shfl_down(a, o, 64); bb += __shfl_down(bb, o, 64); }
    if ((t & 63) == 0){ smem[t >> 6] = a; smem[4 + (t >> 6)] = bb; }
    __syncthreads();
    if (t == 0){
      su1[n] = smem[0] + smem[1] + smem[2] + smem[3];
      sv1[n] = smem[4] + smem[5] + smem[6] + smem[7];
    }
  } else {
    float* sp  = smem;          // 4096
    float* sp1 = smem + 4096;   // 64
    float* a0  = smem + 4160;   // 64
    float* a1  = smem + 4224;   // 64
    #pragma unroll
    for (int i = 0; i < 16; ++i){
      const int idx = i * 256 + t;
      const float v = softplusf(icU0[idx]);
      sp[idx] = v;
      spU0[idx] = v;
    }
    if (t < 64){
      const float v1 = softplusf(icU1[t]);
      sp1[t] = v1;
      spU1[t] = v1;
      a0[t] = srelu(icb0[t]);
    }
    __syncthreads();
    {
      const int n = t >> 2, q = t & 3;
      float sAcc = 0.0f;
      #pragma unroll
      for (int j = 0; j < 16; ++j) sAcc += sp[n * 64 + q * 16 + j] * a0[q * 16 + j];
      sAcc += __shfl_down(sAcc, 2, 64);
      sAcc += __shfl_down(sAcc, 1, 64);
      if (q == 0) a1[n] = srelu(sAcc + icb1[n]);
    }
    __syncthreads();
    if (t < 64){
      float v = sp1[t] * a1[t];
      #pragma unroll
      for (int o = 32; o > 0; o >>= 1) v += __shfl_down(v, o, 64);
      if (t == 0) z0out[0] = srelu(v + icb2[0]);
    }
  }
}

// per-row: state->bf16, Hu=sigmoid(u/0.1)->bf16, u0/v0 arrays
__global__ __launch_bounds__(256) void prep_state(const float* __restrict__ state,
    bfraw* __restrict__ stateb, bfraw* __restrict__ hub,
    float* __restrict__ u0a, float* __restrict__ v0a){
  const int row = blockIdx.x;
  const int t = threadIdx.x;
  const float* srow = state + (size_t)row * 2048;
  float4 u4 = *reinterpret_cast<const float4*>(srow + t * 4);
  float4 v4 = *reinterpret_cast<const float4*>(srow + 1024 + t * 4);
  float us[4] = {u4.x, u4.y, u4.z, u4.w};
  float vs[4] = {v4.x, v4.y, v4.z, v4.w};
  #pragma unroll
  for (int i = 0; i < 4; ++i){
    const int j = t * 4 + i;
    const float u = us[i], v = vs[i];
    stateb[(size_t)row * 2048 + j] = f2b(u);
    stateb[(size_t)row * 2048 + 1024 + j] = f2b(v);
    hub[(size_t)row * 1024 + j] = f2b(1.0f / (1.0f + expf(-10.0f * u)));
  }
  if (t == 0){ u0a[row] = srow[0]; v0a[row] = srow[1024]; }
}

// fused z2 + V column; reads bf16 stateb
__global__ __launch_bounds__(256) void v2_kernel(const bfraw* __restrict__ stateb, const float* __restrict__ icW2,
    const float* __restrict__ z1f, const float* __restrict__ z2pre,
    const float* __restrict__ spU0, const float* __restrict__ spU1,
    const float* __restrict__ z0p, const float* __restrict__ icb2, float* __restrict__ out){
  const int row = blockIdx.x;
  const int t = threadIdx.x;
  __shared__ float z1s[64];
  __shared__ float s1[4], s2[4];
  if (t < 64) z1s[t] = z1f[(size_t)row * 64 + t];
  short8 xv = reinterpret_cast<const short8*>(stateb + (size_t)row * 2048)[t];
  float4 w0 = reinterpret_cast<const float4*>(icW2)[t * 2];
  float4 w1 = reinterpret_cast<const float4*>(icW2)[t * 2 + 1];
  float wv[8] = {w0.x, w0.y, w0.z, w0.w, w1.x, w1.y, w1.z, w1.w};
  float d = 0.0f, ss = 0.0f;
  #pragma unroll
  for (int e = 0; e < 8; ++e){
    const float x = b2f((bfraw)xv[e]);
    d  = fmaf(wv[e], x, d);
    ss = fmaf(x, x, ss);
  }
  #pragma unroll
  for (int o = 32; o > 0; o >>= 1){ d += __shfl_down(d, o, 64); ss += __shfl_down(ss, o, 64); }
  if ((t & 63) == 0){ s1[t >> 6] = d; s2[t >> 6] = ss; }
  __syncthreads();
  if (t < 64){
    float acc2 = z2pre[(size_t)row * 64 + t];
    #pragma unroll 8
    for (int j = 0; j < 64; ++j) acc2 += spU0[t * 64 + j] * z1s[j];
    float dd = spU1[t] * srelu(acc2);
    #pragma unroll
    for (int o = 32; o > 0; o >>= 1) dd += __shfl_down(dd, o, 64);
    if (t == 0){
      const float D = dd + s1[0] + s1[1] + s1[2] + s1[3];
      const float S = s2[0] + s2[1] + s2[2] + s2[3];
      const float z3 = srelu(D + icb2[0]);
      out[(size_t)row * 2049 + 2048] = srelu(z3 - z0p[0]) + 0.001f * S;
    }
  }
}

// ---------------- MFMA NT-GEMM: triple-buffered LDS, counted vmcnt, XOR-swizzled (BK=64) ----------------
// EPI: 0 = plain bf16 store (Lm) | 2 = tanh(+bias)->bf16 | 4 = h1/z1/z2 split
template<int EPI, int TM, int TN>
__global__ __launch_bounds__(512)
void gemm_nt(const bfraw* __restrict__ A, const bfraw* __restrict__ B,
             int N, int K,
             const float* __restrict__ bias,
             bfraw* __restrict__ outb,
             const float* __restrict__ u0a, const float* __restrict__ v0a,
             const float* __restrict__ su1, const float* __restrict__ sv1,
             const float* __restrict__ icb0, const float* __restrict__ icb1,
             float* __restrict__ z1f, float* __restrict__ z2pre)
{
  constexpr int MF = TM / 32;
  constexpr int NF = TN / 64;
  constexpr int LPB = TM / 64 + TN / 64;   // gload16 ops per wave per stage
  __shared__ bfraw lA[3][TM * 64];
  __shared__ bfraw lB[3][TN * 64];
  const int tid = threadIdx.x;
  const int w  = tid >> 6;
  const int l  = tid & 63;
  const int wr = w >> 2;
  const int wc = w & 3;
  const int bm = blockIdx.x;
  const int bn = blockIdx.y;
  const int lr = l & 15;
  const int q  = l >> 4;

  f32x4 acc[MF][NF] = {};
  const int nt = K >> 6;

  auto stage = [&](int buf, int k0){
    #pragma unroll
    for (int j = 0; j < TM / 64; ++j){
      const int c = j * 512 + tid;
      const int r = c >> 3;
      const int kc = (c & 7) ^ (r & 7);
      gload16(A + (size_t)(bm * TM + r) * K + k0 + kc * 8, &lA[buf][(size_t)(j * 512 + w * 64) * 8]);
    }
    #pragma unroll
    for (int j = 0; j < TN / 64; ++j){
      const int c = j * 512 + tid;
      const int r = c >> 3;
      const int kc = (c & 7) ^ (r & 7);
      gload16(B + (size_t)(bn * TN + r) * K + k0 + kc * 8, &lB[buf][(size_t)(j * 512 + w * 64) * 8]);
    }
  };

  stage(0, 0);
  stage(1, 64);
  for (int t = 0; t < nt; ++t){
    const int cur = t % 3;
    if (t == nt - 1) wait_vm<0>(); else wait_vm<LPB>();
    block_barrier();
    short8 aF[2][MF], bF[2][NF];
    #pragma unroll
    for (int kh = 0; kh < 2; ++kh){
      #pragma unroll
      for (int m = 0; m < MF; ++m){
        const int R = wr * (TM / 2) + m * 16 + lr;
        const int kch = (kh * 4 + q) ^ (lr & 7);
        aF[kh][m] = *reinterpret_cast<const short8*>(&lA[cur][(size_t)R * 64 + kch * 8]);
      }
      #pragma unroll
      for (int n = 0; n < NF; ++n){
        const int R = wc * (TN / 4) + n * 16 + lr;
        const int kch = (kh * 4 + q) ^ (lr & 7);
        bF[kh][n] = *reinterpret_cast<const short8*>(&lB[cur][(size_t)R * 64 + kch * 8]);
      }
    }
    if (t + 2 < nt) stage((t + 2) % 3, (t + 2) * 64);
    #pragma unroll
    for (int kh = 0; kh < 2; ++kh){
      #pragma unroll
      for (int m = 0; m < MF; ++m){
        #pragma unroll
        for (int n = 0; n < NF; ++n){
          acc[m][n] = __builtin_amdgcn_mfma_f32_16x16x32_bf16(aF[kh][m], bF[kh][n], acc[m][n], 0, 0, 0);
        }
      }
    }
  }

  #pragma unroll
  for (int m = 0; m < MF; ++m){
    #pragma unroll
    for (int n = 0; n < NF; ++n){
      #pragma unroll
      for (int r = 0; r < 4; ++r){
        const int row = bm * TM + wr * (TM / 2) + m * 16 + q * 4 + r;
        const int col = bn * TN + wc * (TN / 4) + n * 16 + lr;
        const float v = acc[m][n][r];
        if constexpr (EPI == 0){
          outb[(size_t)row * N + col] = f2b(v);
        } else if constexpr (EPI == 2){
          outb[(size_t)row * N + col] = f2b(tanhf(v + bias[col]));
        } else if constexpr (EPI == 4){
          if (col < 512){
            const float h = v - u0a[row] * su1[col] - v0a[row] * sv1[col] + bias[col];
            outb[(size_t)row * 512 + col] = f2b(tanhf(h));
          } else if (col < 576){
            z1f[(size_t)row * 64 + (col - 512)] = srelu(v + icb0[col - 512]);
          } else {
            z2pre[(size_t)row * 64 + (col - 576)] = v + icb1[col - 576];
          }
        }
      }
    }
  }
}

// ---------------- col-paired output GEMM: uniform work, TM=128, paired TN=64 ----------------
// Block (bm,bn) handles cols [bn*64,+64) AND [1024+bn*64,+64).
// Phase 1 (8 tiles): un for BOTH col slices, A (h2b panel) staged ONCE -> acc2 (lo), acc3 (hi).
// -> write hi cols (dv + clamp(un_hi*(v-v0))).  acc3 dies.
// Phase 2 (16 tiles): du over Lm -> acc1.  -> write lo cols (du + cubic + clamp(un_lo*(u-u0))).
// 512 thr (8 waves 2x4), wave tile 64x16; single 32KB LDS; proven BK=64 swizzle; uniform 24 tiles.
__global__ __launch_bounds__(512, 4)
void gemm_out(const bfraw* __restrict__ hub, const bfraw* __restrict__ lm,
              const bfraw* __restrict__ h2b, const bfraw* __restrict__ w3b,
              const bfraw* __restrict__ stateb, const float* __restrict__ b3,
              const float* __restrict__ u0a, const float* __restrict__ v0a,
              float* __restrict__ out)
{
  __shared__ bfraw lA[128 * 64];    // 16KB
  __shared__ bfraw lBlo[64 * 64];   // 8KB
  __shared__ bfraw lBhi[64 * 64];   // 8KB
  const int tid = threadIdx.x;      // 512
  const int w  = tid >> 6;          // 0..7
  const int l  = tid & 63;
  const int wr = w >> 2;            // 0..1
  const int wc = w & 3;             // 0..3
  const int bm = blockIdx.x;        // 0..31
  const int bn = blockIdx.y;        // 0..15
  const int lr = l & 15;
  const int q  = l >> 4;

  const bfraw* Ah  = hub + (size_t)(bm * 128) * 1024;          // du A
  const bfraw* Bl  = lm  + (size_t)(bn * 64) * 1024;           // du B
  const bfraw* Au  = h2b + (size_t)(bm * 128) * 512;           // un A
  const bfraw* Bwl = w3b + (size_t)(bn * 64) * 512;            // un B lo
  const bfraw* Bwh = w3b + (size_t)(1024 + bn * 64) * 512;     // un B hi

  f32x4 acc2[4] = {};   // un lo
  f32x4 acc3[4] = {};   // un hi

  // ---------- phase 1: un combined (K=512, 8 tiles) ----------
  for (int t = 0; t < 8; ++t){
    const int k0 = t * 64;
    #pragma unroll
    for (int j = 0; j < 2; ++j){
      const int c = j * 512 + tid;
      const int r = c >> 3;
      const int kc = (c & 7) ^ (r & 7);
      gload16(Au + (size_t)r * 512 + k0 + kc * 8, &lA[(size_t)(j * 512 + w * 64) * 8]);
    }
    {
      const int r = tid >> 3;
      const int kc = (tid & 7) ^ (r & 7);
      gload16(Bwl + (size_t)r * 512 + k0 + kc * 8, &lBlo[(size_t)(w * 64) * 8]);
      gload16(Bwh + (size_t)r * 512 + k0 + kc * 8, &lBhi[(size_t)(w * 64) * 8]);
    }
    __syncthreads();
    short8 aF[2][4], bL[2], bH[2];
    #pragma unroll
    for (int kh = 0; kh < 2; ++kh){
      const int kch = (kh * 4 + q) ^ (lr & 7);
      #pragma unroll
      for (int m = 0; m < 4; ++m){
        const int R = wr * 64 + m * 16 + lr;
        aF[kh][m] = *reinterpret_cast<const short8*>(&lA[(size_t)R * 64 + kch * 8]);
      }
      const int R = wc * 16 + lr;
      bL[kh] = *reinterpret_cast<const short8*>(&lBlo[(size_t)R * 64 + kch * 8]);
      bH[kh] = *reinterpret_cast<const short8*>(&lBhi[(size_t)R * 64 + kch * 8]);
    }
    #pragma unroll
    for (int kh = 0; kh < 2; ++kh){
      #pragma unroll
      for (int m = 0; m < 4; ++m){
        acc2[m] = __builtin_amdgcn_mfma_f32_16x16x32_bf16(aF[kh][m], bL[kh], acc2[m], 0, 0, 0);
        acc3[m] = __builtin_amdgcn_mfma_f32_16x16x32_bf16(aF[kh][m], bH[kh], acc3[m], 0, 0, 0);
      }
    }
    __syncthreads();
  }

  // ---------- write hi cols: dv + clamp(un_hi * (v - v0)) ----------
  #pragma unroll
  for (int m = 0; m < 4; ++m){
    #pragma unroll
    for (int r = 0; r < 4; ++r){
      const int row = bm * 128 + wr * 64 + m * 16 + q * 4 + r;
      const int c   = bn * 64 + wc * 16 + lr;            // 0..1023
      const float un = acc3[m][r] + b3[1024 + c];
      const float u  = b2f(stateb[(size_t)row * 2048 + c]);
      const float vv = b2f(stateb[(size_t)row * 2048 + 1024 + c]);
      const float x  = vv - v0a[row];
      const float ux = un * x;
      const float cl = (ux < 10.0f && -10.0f < ux) ? ux : 0.0f;
      out[(size_t)row * 2049 + 1024 + c] = 0.2f * (u + 0.7f - 0.8f * vv) + cl;
    }
  }

  // ---------- phase 2: du (K=1024, 16 tiles) ----------
  f32x4 acc1[4] = {};
  for (int t = 0; t < 16; ++t){
    const int k0 = t * 64;
    #pragma unroll
    for (int j = 0; j < 2; ++j){
      const int c = j * 512 + tid;
      const int r = c >> 3;
      const int kc = (c & 7) ^ (r & 7);
      gload16(Ah + (size_t)r * 1024 + k0 + kc * 8, &lA[(size_t)(j * 512 + w * 64) * 8]);
    }
    {
      const int r = tid >> 3;
      const int kc = (tid & 7) ^ (r & 7);
      gload16(Bl + (size_t)r * 1024 + k0 + kc * 8, &lBlo[(size_t)(w * 64) * 8]);
    }
    __syncthreads();
    short8 aF[2][4], bL[2];
    #pragma unroll
    for (int kh = 0; kh < 2; ++kh){
      const int kch = (kh * 4 + q) ^ (lr & 7);
      #pragma unroll
      for (int m = 0; m < 4; ++m){
        const int R = wr * 64 + m * 16 + lr;
        aF[kh][m] = *reinterpret_cast<const short8*>(&lA[(size_t)R * 64 + kch * 8]);
      }
      const int R = wc * 16 + lr;
      bL[kh] = *reinterpret_cast<const short8*>(&lBlo[(size_t)R * 64 + kch * 8]);
    }
    #pragma unroll
    for (int kh = 0; kh < 2; ++kh){
      #pragma unroll
      for (int m = 0; m < 4; ++m){
        acc1[m] = __builtin_amdgcn_mfma_f32_16x16x32_bf16(aF[kh][m], bL[kh], acc1[m], 0, 0, 0);
      }
    }
    __syncthreads();
  }

  // ---------- write lo cols: du + u - u^3/3 - v + 1 + clamp(un_lo * (u - u0)) ----------
  #pragma unroll
  for (int m = 0; m < 4; ++m){
    #pragma unroll
    for (int r = 0; r < 4; ++r){
      const int row = bm * 128 + wr * 64 + m * 16 + q * 4 + r;
      const int c   = bn * 64 + wc * 16 + lr;
      const float un = acc2[m][r] + b3[c];
      const float u  = b2f(stateb[(size_t)row * 2048 + c]);
      const float vv = b2f(stateb[(size_t)row * 2048 + 1024 + c]);
      const float x  = u - u0a[row];
      const float ux = un * x;
      const float cl = (ux < 10.0f && -10.0f < ux) ? ux : 0.0f;
      out[(size_t)row * 2049 + c] = acc1[m][r] + u - u * u * u * (1.0f / 3.0f) - vv + 1.0f + cl;
    }
  }
}

// ---------------- launch ----------------
extern "C" void kernel_launch(void* const* d_in, const int* in_sizes, int n_in,
                              void* d_out, int out_size, void* d_ws, size_t ws_size,
                              hipStream_t stream){
  (void)in_sizes; (void)n_in; (void)out_size; (void)ws_size;
  const float* state = (const float*)d_in[0];
  const float* tp    = (const float*)d_in[1];
  const float* P     = (const float*)d_in[2];
  const float* W1    = (const float*)d_in[3];
  const float* b1    = (const float*)d_in[4];
  const float* W2    = (const float*)d_in[5];
  const float* b2    = (const float*)d_in[6];
  const float* W3    = (const float*)d_in[7];
  const float* b3    = (const float*)d_in[8];
  const float* icW0  = (const float*)d_in[9];
  const float* icb0  = (const float*)d_in[10];
  const float* icW1  = (const float*)d_in[11];
  const float* icb1  = (const float*)d_in[12];
  const float* icW2  = (const float*)d_in[13];
  const float* icb2  = (const float*)d_in[14];
  const float* icU0  = (const float*)d_in[15];
  const float* icU1  = (const float*)d_in[16];
  float* out = (float*)d_out;
  char* ws = (char*)d_ws;

  bfraw* stateb = (bfraw*)(ws + OFF_STATEB);
  bfraw* hub    = (bfraw*)(ws + OFF_HUB);
  bfraw* pt     = (bfraw*)(ws + OFF_PT);
  bfraw* pteig  = (bfraw*)(ws + OFF_PTEIG);
  bfraw* lm     = (bfraw*)(ws + OFF_LM);
  bfraw* w1zb   = (bfraw*)(ws + OFF_W1ZB);
  bfraw* w2b    = (bfraw*)(ws + OFF_W2B);
  bfraw* w3b    = (bfraw*)(ws + OFF_W3B);
  bfraw* h1b    = (bfraw*)(ws + OFF_H1B);
  bfraw* h2b    = (bfraw*)(ws + OFF_H2B);
  float* z1f    = (float*)(ws + OFF_Z1F);
  float* z2pre  = (float*)(ws + OFF_Z2PRE);
  float* spU0   = (float*)(ws + OFF_SPU0);
  float* spU1   = (float*)(ws + OFF_SPU1);
  float* z0     = (float*)(ws + OFF_Z0);
  float* su1    = (float*)(ws + OFF_SU1);
  float* sv1    = (float*)(ws + OFF_SV1);
  float* u0a    = (float*)(ws + OFF_U0);
  float* v0a    = (float*)(ws + OFF_V0);

  prep_fused<<<dim3(4097), 256, 0, stream>>>(W1, icW0, icW1, W2, W3, P, tp,
      icU0, icU1, icb0, icb1, icb2,
      w1zb, w2b, w3b, pt, pteig, su1, sv1, spU0, spU1, z0);
  prep_state<<<dim3(4096), 256, 0, stream>>>(state, stateb, hub, u0a, v0a);

  // Lm = (eig*P)^T @ P   (1024x1024, K=1024) -> bf16
  gemm_nt<0, 64, 64><<<dim3(16, 16), 512, 0, stream>>>(pteig, pt, 1024, 1024,
      nullptr, lm, nullptr, nullptr, nullptr, nullptr, nullptr, nullptr, nullptr, nullptr);
  // h1 = tanh(state@W1^T - u0*su1 - v0*sv1 + b1) ; z1 ; z2pre   (4096x640, K=2048)
  gemm_nt<4, 64, 128><<<dim3(64, 5), 512, 0, stream>>>(stateb, w1zb, 640, 2048,
      b1, h1b, u0a, v0a, su1, sv1, icb0, icb1, z1f, z2pre);
  // h2 = tanh(h1 @ W2^T + b2)   (4096x512, K=512)
  gemm_nt<2, 64, 128><<<dim3(64, 4), 512, 0, stream>>>(h1b, w2b, 512, 512,
      b2, h2b, nullptr, nullptr, nullptr, nullptr, nullptr, nullptr, nullptr, nullptr);
  // out[:, :2048] (col-paired, uniform dual-K fused GEMM)
  gemm_out<<<dim3(32, 16), 512, 0, stream>>>(hub, lm, h2b, w3b, stateb, b3, u0a, v0a, out);

  v2_kernel<<<dim3(4096), 256, 0, stream>>>(stateb, icW2, z1f, z2pre, spU0, spU1, z0, icb2, out);
}

// Round 12
// 106.325 us; speedup vs baseline: 1.1632x; 1.0364x over previous
//
#include <hip/hip_runtime.h>
#include <hip/hip_fp8.h>
#include <cstdint>
#include <cstddef>

using short8 = __attribute__((ext_vector_type(8))) short;
using f32x4  = __attribute__((ext_vector_type(4))) float;
using bfraw  = unsigned short;

// ---------------- helpers ----------------
__device__ __forceinline__ bfraw f2b(float f){
  unsigned int u = __builtin_bit_cast(unsigned int, f);
  u += 0x7FFFu + ((u >> 16) & 1u);            // round-to-nearest-even
  return (bfraw)(u >> 16);
}
__device__ __forceinline__ float b2f(bfraw h){
  unsigned int u = ((unsigned int)h) << 16;
  return __builtin_bit_cast(float, u);
}
__device__ __forceinline__ unsigned char f2f8(float f){   // OCP e4m3fn
  __hip_fp8_e4m3 t(f);
  return (unsigned char)t.__x;
}
__device__ __forceinline__ float srelu(float x){ // smooth_relu, d=0.1
  float r = fmaxf(x, 0.0f);
  if (r < 0.1f){ float r2 = r * r; return (0.2f * r2 * r - r2 * r2) * 500.0f; }
  return x - 0.05f;
}
__device__ __forceinline__ float softplusf(float x){
  return (x > 15.0f) ? x : log1pf(expf(x));
}
__device__ __forceinline__ void gload16(const void* g, void* s){
  __builtin_amdgcn_global_load_lds((const __attribute__((address_space(1))) void*)g,
                                   (__attribute__((address_space(3))) void*)s, 16, 0, 0);
}
// counted vmcnt wait (T4)
template<int N> __device__ __forceinline__ void wait_vm(){
  if constexpr (N == 0)      asm volatile("s_waitcnt vmcnt(0)" ::: "memory");
  else if constexpr (N == 2) asm volatile("s_waitcnt vmcnt(2)" ::: "memory");
  else if constexpr (N == 3) asm volatile("s_waitcnt vmcnt(3)" ::: "memory");
  else                       asm volatile("s_waitcnt vmcnt(4)" ::: "memory");
}
__device__ __forceinline__ void block_barrier(){
  __builtin_amdgcn_s_barrier();
  asm volatile("" ::: "memory");
}

// ---------------- workspace layout (bytes) ----------------
constexpr size_t OFF_STATEB = 0;               // 4096*2048 bf16 = 16MB
constexpr size_t OFF_HUB    = 16777216;        // 4096*1024 fp8 = 4MB (8MB reserved)
constexpr size_t OFF_PT     = 27262976;        // 1024*1024 bf16 (P^T)
constexpr size_t OFF_PTEIG  = 29360128;        // 1024*1024 bf16 ((eig*P)^T)
constexpr size_t OFF_LM     = 31457280;        // 1024*1024 fp8 (Lm)
constexpr size_t OFF_W1ZB   = 37748736;        // 640*2048 bf16 (W1‖icW0‖icW1)
constexpr size_t OFF_W2B    = 40370176;        // 512*512 bf16
constexpr size_t OFF_W3B    = 40894464;        // 2048*512 fp8
constexpr size_t OFF_H1B    = 42991616;        // 4096*512 bf16
constexpr size_t OFF_H2B    = 47185920;        // 4096*512 fp8
constexpr size_t OFF_Z1F    = 51380224;        // 4096*64 f32
constexpr size_t OFF_Z2PRE  = 52428800;        // 4096*64 f32
constexpr size_t OFF_SPU0   = 54525952;        // 64*64 f32
constexpr size_t OFF_SPU1   = 54542336;        // 64 f32
constexpr size_t OFF_Z0     = 54542592;        // 1 f32 (padded)
constexpr size_t OFF_SU1    = 54542848;        // 512 f32
constexpr size_t OFF_SV1    = 54544896;        // 512 f32
constexpr size_t OFF_U0     = 54546944;        // 4096 f32
constexpr size_t OFF_V0     = 54563328;        // 4096 f32

// ---------------- fused prep: weights cast | P transpose(+eig) | W1 rowsums | icnn tables ----------------
__global__ __launch_bounds__(256) void prep_fused(const float* __restrict__ W1,
    const float* __restrict__ icW0, const float* __restrict__ icW1,
    const float* __restrict__ W2, const float* __restrict__ W3,
    const float* __restrict__ P, const float* __restrict__ tptr,
    const float* __restrict__ icU0, const float* __restrict__ icU1,
    const float* __restrict__ icb0, const float* __restrict__ icb1, const float* __restrict__ icb2,
    bfraw* __restrict__ w1zb, bfraw* __restrict__ w2b, unsigned char* __restrict__ w3f8,
    bfraw* __restrict__ PT, bfraw* __restrict__ PTeig,
    float* __restrict__ su1, float* __restrict__ sv1,
    float* __restrict__ spU0, float* __restrict__ spU1, float* __restrict__ z0out){
  __shared__ float smem[4288];
  const int b = blockIdx.x;
  const int t = threadIdx.x;
  if (b < 2560){
    const int i4 = (b * 256 + t) * 4;
    if (i4 < 1572864){
      const float* src; bfraw* dst; int off;
      if (i4 < 1048576)      { src = W1;   dst = w1zb;           off = i4; }
      else if (i4 < 1179648) { src = icW0; dst = w1zb + 1048576; off = i4 - 1048576; }
      else if (i4 < 1310720) { src = icW1; dst = w1zb + 1179648; off = i4 - 1179648; }
      else                   { src = W2;   dst = w2b;            off = i4 - 1310720; }
      float4 v = *reinterpret_cast<const float4*>(src + off);
      ushort4 o;
      o.x = f2b(v.x); o.y = f2b(v.y); o.z = f2b(v.z); o.w = f2b(v.w);
      *reinterpret_cast<ushort4*>(dst + off) = o;
    } else {
      const int off = i4 - 1572864;                 // W3 -> fp8
      float4 v = *reinterpret_cast<const float4*>(W3 + off);
      uchar4 o;
      o.x = f2f8(v.x); o.y = f2f8(v.y); o.z = f2f8(v.z); o.w = f2f8(v.w);
      *reinterpret_cast<uchar4*>(w3f8 + off) = o;
    }
  } else if (b < 3584){
    float (*tile)[33] = (float(*)[33])smem;
    const int idx = b - 2560;
    const int bi = idx >> 5, bj = idx & 31;
    const int tx = t & 31, ty = t >> 5;
    #pragma unroll
    for (int r = 0; r < 4; ++r){
      const int k = bj * 32 + ty + r * 8;
      const int i = bi * 32 + tx;
      tile[ty + r * 8][tx] = P[(size_t)k * 1024 + i];
    }
    __syncthreads();
    const float s = 2.0f * sinf(tptr[0]);
    #pragma unroll
    for (int r = 0; r < 4; ++r){
      const int i = bi * 32 + ty + r * 8;
      const int k = bj * 32 + tx;
      const float p = tile[tx][ty + r * 8];
      const float e = (k == 0) ? 0.0f : ((k <= 511) ? (1.0f + s) : (1.0f - s));
      PT[(size_t)i * 1024 + k] = f2b(p);
      PTeig[(size_t)i * 1024 + k] = f2b(e * p);
    }
  } else if (b < 4096){
    const int n = b - 3584;
    float a = 0.0f, bb = 0.0f;
    for (int j = t; j < 1024; j += 256) a += W1[(size_t)n * 2048 + j];
    for (int j = t; j < 1024; j += 256) bb += W1[(size_t)n * 2048 + 1024 + j];
    #pragma unroll
    for (int o = 32; o > 0; o >>= 1){ a += __shfl_down(a, o, 64); bb += __shfl_down(bb, o, 64); }
    if ((t & 63) == 0){ smem[t >> 6] = a; smem[4 + (t >> 6)] = bb; }
    __syncthreads();
    if (t == 0){
      su1[n] = smem[0] + smem[1] + smem[2] + smem[3];
      sv1[n] = smem[4] + smem[5] + smem[6] + smem[7];
    }
  } else {
    float* sp  = smem;          // 4096
    float* sp1 = smem + 4096;   // 64
    float* a0  = smem + 4160;   // 64
    float* a1  = smem + 4224;   // 64
    #pragma unroll
    for (int i = 0; i < 16; ++i){
      const int idx = i * 256 + t;
      const float v = softplusf(icU0[idx]);
      sp[idx] = v;
      spU0[idx] = v;
    }
    if (t < 64){
      const float v1 = softplusf(icU1[t]);
      sp1[t] = v1;
      spU1[t] = v1;
      a0[t] = srelu(icb0[t]);
    }
    __syncthreads();
    {
      const int n = t >> 2, q = t & 3;
      float sAcc = 0.0f;
      #pragma unroll
      for (int j = 0; j < 16; ++j) sAcc += sp[n * 64 + q * 16 + j] * a0[q * 16 + j];
      sAcc += __shfl_down(sAcc, 2, 64);
      sAcc += __shfl_down(sAcc, 1, 64);
      if (q == 0) a1[n] = srelu(sAcc + icb1[n]);
    }
    __syncthreads();
    if (t < 64){
      float v = sp1[t] * a1[t];
      #pragma unroll
      for (int o = 32; o > 0; o >>= 1) v += __shfl_down(v, o, 64);
      if (t == 0) z0out[0] = srelu(v + icb2[0]);
    }
  }
}

// per-row: state->bf16, Hu=sigmoid(u/0.1)->fp8, u0/v0 arrays
__global__ __launch_bounds__(256) void prep_state(const float* __restrict__ state,
    bfraw* __restrict__ stateb, unsigned char* __restrict__ hub8,
    float* __restrict__ u0a, float* __restrict__ v0a){
  const int row = blockIdx.x;
  const int t = threadIdx.x;
  const float* srow = state + (size_t)row * 2048;
  float4 u4 = *reinterpret_cast<const float4*>(srow + t * 4);
  float4 v4 = *reinterpret_cast<const float4*>(srow + 1024 + t * 4);
  float us[4] = {u4.x, u4.y, u4.z, u4.w};
  float vs[4] = {v4.x, v4.y, v4.z, v4.w};
  uchar4 h8;
  unsigned char* hp = reinterpret_cast<unsigned char*>(&h8);
  #pragma unroll
  for (int i = 0; i < 4; ++i){
    const int j = t * 4 + i;
    const float u = us[i], v = vs[i];
    stateb[(size_t)row * 2048 + j] = f2b(u);
    stateb[(size_t)row * 2048 + 1024 + j] = f2b(v);
    hp[i] = f2f8(1.0f / (1.0f + expf(-10.0f * u)));
  }
  *reinterpret_cast<uchar4*>(hub8 + (size_t)row * 1024 + t * 4) = h8;
  if (t == 0){ u0a[row] = srow[0]; v0a[row] = srow[1024]; }
}

// fused z2 + V column; reads bf16 stateb
__global__ __launch_bounds__(256) void v2_kernel(const bfraw* __restrict__ stateb, const float* __restrict__ icW2,
    const float* __restrict__ z1f, const float* __restrict__ z2pre,
    const float* __restrict__ spU0, const float* __restrict__ spU1,
    const float* __restrict__ z0p, const float* __restrict__ icb2, float* __restrict__ out){
  const int row = blockIdx.x;
  const int t = threadIdx.x;
  __shared__ float z1s[64];
  __shared__ float s1[4], s2[4];
  if (t < 64) z1s[t] = z1f[(size_t)row * 64 + t];
  short8 xv = reinterpret_cast<const short8*>(stateb + (size_t)row * 2048)[t];
  float4 w0 = reinterpret_cast<const float4*>(icW2)[t * 2];
  float4 w1 = reinterpret_cast<const float4*>(icW2)[t * 2 + 1];
  float wv[8] = {w0.x, w0.y, w0.z, w0.w, w1.x, w1.y, w1.z, w1.w};
  float d = 0.0f, ss = 0.0f;
  #pragma unroll
  for (int e = 0; e < 8; ++e){
    const float x = b2f((bfraw)xv[e]);
    d  = fmaf(wv[e], x, d);
    ss = fmaf(x, x, ss);
  }
  #pragma unroll
  for (int o = 32; o > 0; o >>= 1){ d += __shfl_down(d, o, 64); ss += __shfl_down(ss, o, 64); }
  if ((t & 63) == 0){ s1[t >> 6] = d; s2[t >> 6] = ss; }
  __syncthreads();
  if (t < 64){
    float acc2 = z2pre[(size_t)row * 64 + t];
    #pragma unroll 8
    for (int j = 0; j < 64; ++j) acc2 += spU0[t * 64 + j] * z1s[j];
    float dd = spU1[t] * srelu(acc2);
    #pragma unroll
    for (int o = 32; o > 0; o >>= 1) dd += __shfl_down(dd, o, 64);
    if (t == 0){
      const float D = dd + s1[0] + s1[1] + s1[2] + s1[3];
      const float S = s2[0] + s2[1] + s2[2] + s2[3];
      const float z3 = srelu(D + icb2[0]);
      out[(size_t)row * 2049 + 2048] = srelu(z3 - z0p[0]) + 0.001f * S;
    }
  }
}

// ---------------- MFMA NT-GEMM: triple-buffered LDS, counted vmcnt, XOR-swizzled (BK=64) ----------------
// EPI: 0 = fp8 store (Lm) | 2 = tanh(+bias)->fp8 (h2) | 4 = h1/z1/z2 split (bf16)
template<int EPI, int TM, int TN>
__global__ __launch_bounds__(512)
void gemm_nt(const bfraw* __restrict__ A, const bfraw* __restrict__ B,
             int N, int K,
             const float* __restrict__ bias,
             bfraw* __restrict__ outb, unsigned char* __restrict__ outf8,
             const float* __restrict__ u0a, const float* __restrict__ v0a,
             const float* __restrict__ su1, const float* __restrict__ sv1,
             const float* __restrict__ icb0, const float* __restrict__ icb1,
             float* __restrict__ z1f, float* __restrict__ z2pre)
{
  constexpr int MF = TM / 32;
  constexpr int NF = TN / 64;
  constexpr int LPB = TM / 64 + TN / 64;
  __shared__ bfraw lA[3][TM * 64];
  __shared__ bfraw lB[3][TN * 64];
  const int tid = threadIdx.x;
  const int w  = tid >> 6;
  const int l  = tid & 63;
  const int wr = w >> 2;
  const int wc = w & 3;
  const int bm = blockIdx.x;
  const int bn = blockIdx.y;
  const int lr = l & 15;
  const int q  = l >> 4;

  f32x4 acc[MF][NF] = {};
  const int nt = K >> 6;

  auto stage = [&](int buf, int k0){
    #pragma unroll
    for (int j = 0; j < TM / 64; ++j){
      const int c = j * 512 + tid;
      const int r = c >> 3;
      const int kc = (c & 7) ^ (r & 7);
      gload16(A + (size_t)(bm * TM + r) * K + k0 + kc * 8, &lA[buf][(size_t)(j * 512 + w * 64) * 8]);
    }
    #pragma unroll
    for (int j = 0; j < TN / 64; ++j){
      const int c = j * 512 + tid;
      const int r = c >> 3;
      const int kc = (c & 7) ^ (r & 7);
      gload16(B + (size_t)(bn * TN + r) * K + k0 + kc * 8, &lB[buf][(size_t)(j * 512 + w * 64) * 8]);
    }
  };

  stage(0, 0);
  stage(1, 64);
  for (int t = 0; t < nt; ++t){
    const int cur = t % 3;
    if (t == nt - 1) wait_vm<0>(); else wait_vm<LPB>();
    block_barrier();
    short8 aF[2][MF], bF[2][NF];
    #pragma unroll
    for (int kh = 0; kh < 2; ++kh){
      #pragma unroll
      for (int m = 0; m < MF; ++m){
        const int R = wr * (TM / 2) + m * 16 + lr;
        const int kch = (kh * 4 + q) ^ (lr & 7);
        aF[kh][m] = *reinterpret_cast<const short8*>(&lA[cur][(size_t)R * 64 + kch * 8]);
      }
      #pragma unroll
      for (int n = 0; n < NF; ++n){
        const int R = wc * (TN / 4) + n * 16 + lr;
        const int kch = (kh * 4 + q) ^ (lr & 7);
        bF[kh][n] = *reinterpret_cast<const short8*>(&lB[cur][(size_t)R * 64 + kch * 8]);
      }
    }
    if (t + 2 < nt) stage((t + 2) % 3, (t + 2) * 64);
    #pragma unroll
    for (int kh = 0; kh < 2; ++kh){
      #pragma unroll
      for (int m = 0; m < MF; ++m){
        #pragma unroll
        for (int n = 0; n < NF; ++n){
          acc[m][n] = __builtin_amdgcn_mfma_f32_16x16x32_bf16(aF[kh][m], bF[kh][n], acc[m][n], 0, 0, 0);
        }
      }
    }
  }

  #pragma unroll
  for (int m = 0; m < MF; ++m){
    #pragma unroll
    for (int n = 0; n < NF; ++n){
      #pragma unroll
      for (int r = 0; r < 4; ++r){
        const int row = bm * TM + wr * (TM / 2) + m * 16 + q * 4 + r;
        const int col = bn * TN + wc * (TN / 4) + n * 16 + lr;
        const float v = acc[m][n][r];
        if constexpr (EPI == 0){
          outf8[(size_t)row * N + col] = f2f8(v);
        } else if constexpr (EPI == 2){
          outf8[(size_t)row * N + col] = f2f8(tanhf(v + bias[col]));
        } else if constexpr (EPI == 4){
          if (col < 512){
            const float h = v - u0a[row] * su1[col] - v0a[row] * sv1[col] + bias[col];
            outb[(size_t)row * 512 + col] = f2b(tanhf(h));
          } else if (col < 576){
            z1f[(size_t)row * 64 + (col - 512)] = srelu(v + icb0[col - 512]);
          } else {
            z2pre[(size_t)row * 64 + (col - 576)] = v + icb1[col - 576];
          }
        }
      }
    }
  }
}

// ---------------- col-paired output GEMM, FP8 inputs, BK=128 ----------------
// Block (bm,bn): cols [bn*64,+64) AND [1024+bn*64,+64).
// Phase 1 (4 tiles, K=512): un lo+hi, A (h2 fp8 panel) staged once -> acc2/acc3; write hi.
// Phase 2 (8 tiles, K=1024): du over fp8 Lm -> acc1; write lo.
// 128B LDS rows -> proven 8-chunk XOR swizzle; mfma 16x16x32 fp8_fp8 (same frag geometry).
__global__ __launch_bounds__(512, 4)
void gemm_out(const unsigned char* __restrict__ hub8, const unsigned char* __restrict__ lm8,
              const unsigned char* __restrict__ h2b8, const unsigned char* __restrict__ w3f8,
              const bfraw* __restrict__ stateb, const float* __restrict__ b3,
              const float* __restrict__ u0a, const float* __restrict__ v0a,
              float* __restrict__ out)
{
  __shared__ unsigned char lA[128 * 128];    // 16KB
  __shared__ unsigned char lBlo[64 * 128];   // 8KB
  __shared__ unsigned char lBhi[64 * 128];   // 8KB
  const int tid = threadIdx.x;      // 512
  const int w  = tid >> 6;          // 0..7
  const int l  = tid & 63;
  const int wr = w >> 2;            // 0..1
  const int wc = w & 3;             // 0..3
  const int bm = blockIdx.x;        // 0..31
  const int bn = blockIdx.y;        // 0..15
  const int lr = l & 15;
  const int q  = l >> 4;

  const unsigned char* Au  = h2b8 + (size_t)(bm * 128) * 512;
  const unsigned char* Bwl = w3f8 + (size_t)(bn * 64) * 512;
  const unsigned char* Bwh = w3f8 + (size_t)(1024 + bn * 64) * 512;
  const unsigned char* Ah  = hub8 + (size_t)(bm * 128) * 1024;
  const unsigned char* Bl  = lm8  + (size_t)(bn * 64) * 1024;

  f32x4 acc2[4] = {};   // un lo
  f32x4 acc3[4] = {};   // un hi

  // ---------- phase 1: un combined (K=512, 4 tiles of BK=128) ----------
  for (int t = 0; t < 4; ++t){
    const int k0 = t * 128;
    #pragma unroll
    for (int j = 0; j < 2; ++j){
      const int c = j * 512 + tid;
      const int r = c >> 3;
      const int kc = (c & 7) ^ (r & 7);
      gload16(Au + (size_t)r * 512 + k0 + kc * 16, &lA[(size_t)(j * 512 + w * 64) * 16]);
    }
    {
      const int r = tid >> 3;
      const int kc = (tid & 7) ^ (r & 7);
      gload16(Bwl + (size_t)r * 512 + k0 + kc * 16, &lBlo[(size_t)(w * 64) * 16]);
      gload16(Bwh + (size_t)r * 512 + k0 + kc * 16, &lBhi[(size_t)(w * 64) * 16]);
    }
    __syncthreads();
    #pragma unroll
    for (int kh = 0; kh < 4; ++kh){
      const int ko = kh * 32 + q * 8;              // byte offset of lane's 8 k-elems
      const int ch = (ko >> 4) ^ (lr & 7);         // swizzled 16B chunk
      const int bo = ko & 15;
      long long aF[4], bL, bH;
      #pragma unroll
      for (int m = 0; m < 4; ++m){
        const int R = wr * 64 + m * 16 + lr;
        aF[m] = *reinterpret_cast<const long long*>(&lA[(size_t)R * 128 + ch * 16 + bo]);
      }
      const int Rb = wc * 16 + lr;
      bL = *reinterpret_cast<const long long*>(&lBlo[(size_t)Rb * 128 + ch * 16 + bo]);
      bH = *reinterpret_cast<const long long*>(&lBhi[(size_t)Rb * 128 + ch * 16 + bo]);
      #pragma unroll
      for (int m = 0; m < 4; ++m){
        acc2[m] = __builtin_amdgcn_mfma_f32_16x16x32_fp8_fp8(aF[m], bL, acc2[m], 0, 0, 0);
        acc3[m] = __builtin_amdgcn_mfma_f32_16x16x32_fp8_fp8(aF[m], bH, acc3[m], 0, 0, 0);
      }
    }
    __syncthreads();
  }

  // ---------- write hi cols: dv + clamp(un_hi * (v - v0)) ----------
  #pragma unroll
  for (int m = 0; m < 4; ++m){
    #pragma unroll
    for (int r = 0; r < 4; ++r){
      const int row = bm * 128 + wr * 64 + m * 16 + q * 4 + r;
      const int c   = bn * 64 + wc * 16 + lr;
      const float un = acc3[m][r] + b3[1024 + c];
      const float u  = b2f(stateb[(size_t)row * 2048 + c]);
      const float vv = b2f(stateb[(size_t)row * 2048 + 1024 + c]);
      const float x  = vv - v0a[row];
      const float ux = un * x;
      const float cl = (ux < 10.0f && -10.0f < ux) ? ux : 0.0f;
      out[(size_t)row * 2049 + 1024 + c] = 0.2f * (u + 0.7f - 0.8f * vv) + cl;
    }
  }

  // ---------- phase 2: du (K=1024, 8 tiles of BK=128) ----------
  f32x4 acc1[4] = {};
  for (int t = 0; t < 8; ++t){
    const int k0 = t * 128;
    #pragma unroll
    for (int j = 0; j < 2; ++j){
      const int c = j * 512 + tid;
      const int r = c >> 3;
      const int kc = (c & 7) ^ (r & 7);
      gload16(Ah + (size_t)r * 1024 + k0 + kc * 16, &lA[(size_t)(j * 512 + w * 64) * 16]);
    }
    {
      const int r = tid >> 3;
      const int kc = (tid & 7) ^ (r & 7);
      gload16(Bl + (size_t)r * 1024 + k0 + kc * 16, &lBlo[(size_t)(w * 64) * 16]);
    }
    __syncthreads();
    #pragma unroll
    for (int kh = 0; kh < 4; ++kh){
      const int ko = kh * 32 + q * 8;
      const int ch = (ko >> 4) ^ (lr & 7);
      const int bo = ko & 15;
      long long aF[4], bL;
      #pragma unroll
      for (int m = 0; m < 4; ++m){
        const int R = wr * 64 + m * 16 + lr;
        aF[m] = *reinterpret_cast<const long long*>(&lA[(size_t)R * 128 + ch * 16 + bo]);
      }
      const int Rb = wc * 16 + lr;
      bL = *reinterpret_cast<const long long*>(&lBlo[(size_t)Rb * 128 + ch * 16 + bo]);
      #pragma unroll
      for (int m = 0; m < 4; ++m){
        acc1[m] = __builtin_amdgcn_mfma_f32_16x16x32_fp8_fp8(aF[m], bL, acc1[m], 0, 0, 0);
      }
    }
    __syncthreads();
  }

  // ---------- write lo cols: du + u - u^3/3 - v + 1 + clamp(un_lo * (u - u0)) ----------
  #pragma unroll
  for (int m = 0; m < 4; ++m){
    #pragma unroll
    for (int r = 0; r < 4; ++r){
      const int row = bm * 128 + wr * 64 + m * 16 + q * 4 + r;
      const int c   = bn * 64 + wc * 16 + lr;
      const float un = acc2[m][r] + b3[c];
      const float u  = b2f(stateb[(size_t)row * 2048 + c]);
      const float vv = b2f(stateb[(size_t)row * 2048 + 1024 + c]);
      const float x  = u - u0a[row];
      const float ux = un * x;
      const float cl = (ux < 10.0f && -10.0f < ux) ? ux : 0.0f;
      out[(size_t)row * 2049 + c] = acc1[m][r] + u - u * u * u * (1.0f / 3.0f) - vv + 1.0f + cl;
    }
  }
}

// ---------------- launch ----------------
extern "C" void kernel_launch(void* const* d_in, const int* in_sizes, int n_in,
                              void* d_out, int out_size, void* d_ws, size_t ws_size,
                              hipStream_t stream){
  (void)in_sizes; (void)n_in; (void)out_size; (void)ws_size;
  const float* state = (const float*)d_in[0];
  const float* tp    = (const float*)d_in[1];
  const float* P     = (const float*)d_in[2];
  const float* W1    = (const float*)d_in[3];
  const float* b1    = (const float*)d_in[4];
  const float* W2    = (const float*)d_in[5];
  const float* b2    = (const float*)d_in[6];
  const float* W3    = (const float*)d_in[7];
  const float* b3    = (const float*)d_in[8];
  const float* icW0  = (const float*)d_in[9];
  const float* icb0  = (const float*)d_in[10];
  const float* icW1  = (const float*)d_in[11];
  const float* icb1  = (const float*)d_in[12];
  const float* icW2  = (const float*)d_in[13];
  const float* icb2  = (const float*)d_in[14];
  const float* icU0  = (const float*)d_in[15];
  const float* icU1  = (const float*)d_in[16];
  float* out = (float*)d_out;
  char* ws = (char*)d_ws;

  bfraw* stateb = (bfraw*)(ws + OFF_STATEB);
  unsigned char* hub8 = (unsigned char*)(ws + OFF_HUB);
  bfraw* pt     = (bfraw*)(ws + OFF_PT);
  bfraw* pteig  = (bfraw*)(ws + OFF_PTEIG);
  unsigned char* lm8  = (unsigned char*)(ws + OFF_LM);
  bfraw* w1zb   = (bfraw*)(ws + OFF_W1ZB);
  bfraw* w2b    = (bfraw*)(ws + OFF_W2B);
  unsigned char* w3f8 = (unsigned char*)(ws + OFF_W3B);
  bfraw* h1b    = (bfraw*)(ws + OFF_H1B);
  unsigned char* h2b8 = (unsigned char*)(ws + OFF_H2B);
  float* z1f    = (float*)(ws + OFF_Z1F);
  float* z2pre  = (float*)(ws + OFF_Z2PRE);
  float* spU0   = (float*)(ws + OFF_SPU0);
  float* spU1   = (float*)(ws + OFF_SPU1);
  float* z0     = (float*)(ws + OFF_Z0);
  float* su1    = (float*)(ws + OFF_SU1);
  float* sv1    = (float*)(ws + OFF_SV1);
  float* u0a    = (float*)(ws + OFF_U0);
  float* v0a    = (float*)(ws + OFF_V0);

  prep_fused<<<dim3(4097), 256, 0, stream>>>(W1, icW0, icW1, W2, W3, P, tp,
      icU0, icU1, icb0, icb1, icb2,
      w1zb, w2b, w3f8, pt, pteig, su1, sv1, spU0, spU1, z0);
  prep_state<<<dim3(4096), 256, 0, stream>>>(state, stateb, hub8, u0a, v0a);

  // Lm = (eig*P)^T @ P   (1024x1024, K=1024) -> fp8
  gemm_nt<0, 64, 64><<<dim3(16, 16), 512, 0, stream>>>(pteig, pt, 1024, 1024,
      nullptr, nullptr, lm8, nullptr, nullptr, nullptr, nullptr, nullptr, nullptr, nullptr, nullptr);
  // h1 = tanh(state@W1^T - u0*su1 - v0*sv1 + b1) ; z1 ; z2pre   (4096x640, K=2048)
  gemm_nt<4, 64, 128><<<dim3(64, 5), 512, 0, stream>>>(stateb, w1zb, 640, 2048,
      b1, h1b, nullptr, u0a, v0a, su1, sv1, icb0, icb1, z1f, z2pre);
  // h2 = tanh(h1 @ W2^T + b2) -> fp8   (4096x512, K=512)
  gemm_nt<2, 64, 128><<<dim3(64, 4), 512, 0, stream>>>(h1b, w2b, 512, 512,
      b2, nullptr, h2b8, nullptr, nullptr, nullptr, nullptr, nullptr, nullptr, nullptr, nullptr);
  // out[:, :2048] (col-paired dual-K fused GEMM, fp8 inputs)
  gemm_out<<<dim3(32, 16), 512, 0, stream>>>(hub8, lm8, h2b8, w3f8, stateb, b3, u0a, v0a, out);

  v2_kernel<<<dim3(4096), 256, 0, stream>>>(stateb, icW2, z1f, z2pre, spU0, spU1, z0, icb2, out);
}

// Round 15
// 100.714 us; speedup vs baseline: 1.2280x; 1.0557x over previous
//
#include <hip/hip_runtime.h>
#include <hip/hip_fp8.h>
#include <cstdint>
#include <cstddef>

using short8 = __attribute__((ext_vector_type(8))) short;
using f32x4  = __attribute__((ext_vector_type(4))) float;
using bfraw  = unsigned short;

// ---------------- helpers ----------------
__device__ __forceinline__ bfraw f2b(float f){
  unsigned int u = __builtin_bit_cast(unsigned int, f);
  u += 0x7FFFu + ((u >> 16) & 1u);            // round-to-nearest-even
  return (bfraw)(u >> 16);
}
__device__ __forceinline__ float b2f(bfraw h){
  unsigned int u = ((unsigned int)h) << 16;
  return __builtin_bit_cast(float, u);
}
__device__ __forceinline__ unsigned char f2f8(float f){   // OCP e4m3fn
  __hip_fp8_e4m3 t(f);
  return (unsigned char)t.__x;
}
__device__ __forceinline__ float srelu(float x){ // smooth_relu, d=0.1
  float r = fmaxf(x, 0.0f);
  if (r < 0.1f){ float r2 = r * r; return (0.2f * r2 * r - r2 * r2) * 500.0f; }
  return x - 0.05f;
}
__device__ __forceinline__ float softplusf(float x){
  return (x > 15.0f) ? x : log1pf(expf(x));
}
__device__ __forceinline__ void gload16(const void* g, void* s){
  __builtin_amdgcn_global_load_lds((const __attribute__((address_space(1))) void*)g,
                                   (__attribute__((address_space(3))) void*)s, 16, 0, 0);
}
// counted vmcnt wait (T4)
template<int N> __device__ __forceinline__ void wait_vm(){
  if constexpr (N == 0)      asm volatile("s_waitcnt vmcnt(0)" ::: "memory");
  else if constexpr (N == 2) asm volatile("s_waitcnt vmcnt(2)" ::: "memory");
  else if constexpr (N == 3) asm volatile("s_waitcnt vmcnt(3)" ::: "memory");
  else                       asm volatile("s_waitcnt vmcnt(4)" ::: "memory");
}
__device__ __forceinline__ void block_barrier(){
  __builtin_amdgcn_s_barrier();
  asm volatile("" ::: "memory");
}

// ---------------- workspace layout (bytes) ----------------
constexpr size_t OFF_STATEB = 0;               // 4096*2048 bf16 = 16MB
constexpr size_t OFF_HUB    = 16777216;        // 4096*1024 fp8 = 4MB
constexpr size_t OFF_PT     = 20971520;        // 1024*1024 bf16 = 2MB
constexpr size_t OFF_PTEIG  = 23068672;        // 1024*1024 bf16 = 2MB
constexpr size_t OFF_LM8    = 25165824;        // 1024*1024 fp8 = 1MB
constexpr size_t OFF_W1ZB   = 26214400;        // 640*2048 bf16 = 2.5MB
constexpr size_t OFF_W2B    = 28835840;        // 512*512 bf16 = 0.5MB
constexpr size_t OFF_W38    = 29360128;        // 2048*512 fp8 = 1MB
constexpr size_t OFF_H1B    = 30408704;        // 4096*512 bf16 = 4MB
constexpr size_t OFF_H28    = 34603008;        // 4096*512 fp8 = 2MB
constexpr size_t OFF_Z1F    = 36700160;        // 4096*64 f32 = 1MB
constexpr size_t OFF_Z2PRE  = 37748736;        // 4096*64 f32 = 1MB
constexpr size_t OFF_SPU0   = 38797312;        // 64*64 f32
constexpr size_t OFF_SPU1   = 38813696;        // 64 f32
constexpr size_t OFF_Z0     = 38813952;        // 1 f32 (padded)
constexpr size_t OFF_SU1    = 38814208;        // 512 f32
constexpr size_t OFF_SV1    = 38816256;        // 512 f32
constexpr size_t OFF_U0     = 38818304;        // 4096 f32
constexpr size_t OFF_V0     = 38834688;        // 4096 f32

// ---------------- merged prep (R12 prep_fused + prep_state, mechanically merged) ----------------
// b<2560: cast W1|icW0|icW1|W2 -> bf16, W3 -> fp8.  b<3584: P -> pt,pteig (bf16).
// b<4096: su1/sv1 rowsums.  b==4096: spU0/spU1/z0.  b>4096: per-row state prep.
__global__ __launch_bounds__(256) void prep_all(const float* __restrict__ W1,
    const float* __restrict__ icW0, const float* __restrict__ icW1,
    const float* __restrict__ W2, const float* __restrict__ W3,
    const float* __restrict__ P, const float* __restrict__ tptr,
    const float* __restrict__ icU0, const float* __restrict__ icU1,
    const float* __restrict__ icb0, const float* __restrict__ icb1, const float* __restrict__ icb2,
    const float* __restrict__ state,
    bfraw* __restrict__ w1zb, bfraw* __restrict__ w2b, unsigned char* __restrict__ w3f8,
    bfraw* __restrict__ PT, bfraw* __restrict__ PTeig,
    float* __restrict__ su1, float* __restrict__ sv1,
    float* __restrict__ spU0, float* __restrict__ spU1, float* __restrict__ z0out,
    bfraw* __restrict__ stateb, unsigned char* __restrict__ hub8,
    float* __restrict__ u0a, float* __restrict__ v0a){
  __shared__ float smem[4288];
  const int b = blockIdx.x;
  const int t = threadIdx.x;
  if (b < 2560){
    const int i4 = (b * 256 + t) * 4;
    if (i4 < 1572864){
      const float* src; bfraw* dst; int off;
      if (i4 < 1048576)      { src = W1;   dst = w1zb;           off = i4; }
      else if (i4 < 1179648) { src = icW0; dst = w1zb + 1048576; off = i4 - 1048576; }
      else if (i4 < 1310720) { src = icW1; dst = w1zb + 1179648; off = i4 - 1179648; }
      else                   { src = W2;   dst = w2b;            off = i4 - 1310720; }
      float4 v = *reinterpret_cast<const float4*>(src + off);
      ushort4 o;
      o.x = f2b(v.x); o.y = f2b(v.y); o.z = f2b(v.z); o.w = f2b(v.w);
      *reinterpret_cast<ushort4*>(dst + off) = o;
    } else {
      const int off = i4 - 1572864;                 // W3 -> fp8
      float4 v = *reinterpret_cast<const float4*>(W3 + off);
      uchar4 o;
      o.x = f2f8(v.x); o.y = f2f8(v.y); o.z = f2f8(v.z); o.w = f2f8(v.w);
      *reinterpret_cast<uchar4*>(w3f8 + off) = o;
    }
  } else if (b < 3584){
    float (*tile)[33] = (float(*)[33])smem;
    const int idx = b - 2560;
    const int bi = idx >> 5, bj = idx & 31;
    const int tx = t & 31, ty = t >> 5;
    #pragma unroll
    for (int r = 0; r < 4; ++r){
      const int k = bj * 32 + ty + r * 8;
      const int i = bi * 32 + tx;
      tile[ty + r * 8][tx] = P[(size_t)k * 1024 + i];
    }
    __syncthreads();
    const float s = 2.0f * sinf(tptr[0]);
    #pragma unroll
    for (int r = 0; r < 4; ++r){
      const int i = bi * 32 + ty + r * 8;
      const int k = bj * 32 + tx;
      const float p = tile[tx][ty + r * 8];
      const float e = (k == 0) ? 0.0f : ((k <= 511) ? (1.0f + s) : (1.0f - s));
      PT[(size_t)i * 1024 + k] = f2b(p);
      PTeig[(size_t)i * 1024 + k] = f2b(e * p);
    }
  } else if (b < 4096){
    const int n = b - 3584;
    float a = 0.0f, bb = 0.0f;
    for (int j = t; j < 1024; j += 256) a += W1[(size_t)n * 2048 + j];
    for (int j = t; j < 1024; j += 256) bb += W1[(size_t)n * 2048 + 1024 + j];
    #pragma unroll
    for (int o = 32; o > 0; o >>= 1){ a += __shfl_down(a, o, 64); bb += __shfl_down(bb, o, 64); }
    if ((t & 63) == 0){ smem[t >> 6] = a; smem[4 + (t >> 6)] = bb; }
    __syncthreads();
    if (t == 0){
      su1[n] = smem[0] + smem[1] + smem[2] + smem[3];
      sv1[n] = smem[4] + smem[5] + smem[6] + smem[7];
    }
  } else if (b == 4096){
    float* sp  = smem;          // 4096
    float* sp1 = smem + 4096;   // 64
    float* a0  = smem + 4160;   // 64
    float* a1  = smem + 4224;   // 64
    #pragma unroll
    for (int i = 0; i < 16; ++i){
      const int idx = i * 256 + t;
      const float v = softplusf(icU0[idx]);
      sp[idx] = v;
      spU0[idx] = v;
    }
    if (t < 64){
      const float v1 = softplusf(icU1[t]);
      sp1[t] = v1;
      spU1[t] = v1;
      a0[t] = srelu(icb0[t]);
    }
    __syncthreads();
    {
      const int n = t >> 2, q = t & 3;
      float sAcc = 0.0f;
      #pragma unroll
      for (int j = 0; j < 16; ++j) sAcc += sp[n * 64 + q * 16 + j] * a0[q * 16 + j];
      sAcc += __shfl_down(sAcc, 2, 64);
      sAcc += __shfl_down(sAcc, 1, 64);
      if (q == 0) a1[n] = srelu(sAcc + icb1[n]);
    }
    __syncthreads();
    if (t < 64){
      float v = sp1[t] * a1[t];
      #pragma unroll
      for (int o = 32; o > 0; o >>= 1) v += __shfl_down(v, o, 64);
      if (t == 0) z0out[0] = srelu(v + icb2[0]);
    }
  } else {
    const int row = b - 4097;
    const float* srow = state + (size_t)row * 2048;
    float4 u4 = *reinterpret_cast<const float4*>(srow + t * 4);
    float4 v4 = *reinterpret_cast<const float4*>(srow + 1024 + t * 4);
    float us[4] = {u4.x, u4.y, u4.z, u4.w};
    float vs[4] = {v4.x, v4.y, v4.z, v4.w};
    uchar4 h8;
    unsigned char* hp = reinterpret_cast<unsigned char*>(&h8);
    #pragma unroll
    for (int i = 0; i < 4; ++i){
      const int j = t * 4 + i;
      const float u = us[i], v = vs[i];
      stateb[(size_t)row * 2048 + j] = f2b(u);
      stateb[(size_t)row * 2048 + 1024 + j] = f2b(v);
      hp[i] = f2f8(1.0f / (1.0f + expf(-10.0f * u)));
    }
    *reinterpret_cast<uchar4*>(hub8 + (size_t)row * 1024 + t * 4) = h8;
    if (t == 0){ u0a[row] = srow[0]; v0a[row] = srow[1024]; }
  }
}

// fused z2 + V column; reads bf16 stateb
__global__ __launch_bounds__(256) void v2_kernel(const bfraw* __restrict__ stateb, const float* __restrict__ icW2,
    const float* __restrict__ z1f, const float* __restrict__ z2pre,
    const float* __restrict__ spU0, const float* __restrict__ spU1,
    const float* __restrict__ z0p, const float* __restrict__ icb2, float* __restrict__ out){
  const int row = blockIdx.x;
  const int t = threadIdx.x;
  __shared__ float z1s[64];
  __shared__ float s1[4], s2[4];
  if (t < 64) z1s[t] = z1f[(size_t)row * 64 + t];
  short8 xv = reinterpret_cast<const short8*>(stateb + (size_t)row * 2048)[t];
  float4 w0 = reinterpret_cast<const float4*>(icW2)[t * 2];
  float4 w1 = reinterpret_cast<const float4*>(icW2)[t * 2 + 1];
  float wv[8] = {w0.x, w0.y, w0.z, w0.w, w1.x, w1.y, w1.z, w1.w};
  float d = 0.0f, ss = 0.0f;
  #pragma unroll
  for (int e = 0; e < 8; ++e){
    const float x = b2f((bfraw)xv[e]);
    d  = fmaf(wv[e], x, d);
    ss = fmaf(x, x, ss);
  }
  #pragma unroll
  for (int o = 32; o > 0; o >>= 1){ d += __shfl_down(d, o, 64); ss += __shfl_down(ss, o, 64); }
  if ((t & 63) == 0){ s1[t >> 6] = d; s2[t >> 6] = ss; }
  __syncthreads();
  if (t < 64){
    float acc2 = z2pre[(size_t)row * 64 + t];
    #pragma unroll 8
    for (int j = 0; j < 64; ++j) acc2 += spU0[t * 64 + j] * z1s[j];
    float dd = spU1[t] * srelu(acc2);
    #pragma unroll
    for (int o = 32; o > 0; o >>= 1) dd += __shfl_down(dd, o, 64);
    if (t == 0){
      const float D = dd + s1[0] + s1[1] + s1[2] + s1[3];
      const float S = s2[0] + s2[1] + s2[2] + s2[3];
      const float z3 = srelu(D + icb2[0]);
      out[(size_t)row * 2049 + 2048] = srelu(z3 - z0p[0]) + 0.001f * S;
    }
  }
}

// ---------------- bf16 MFMA NT-GEMM: triple-buffered LDS, counted vmcnt, XOR-swizzled (BK=64) ----------------
// EPI: 0 = fp8 store (Lm) | 2 = tanh(+bias)->fp8 (h2) | 4 = h1(bf16)/z1/z2 split
template<int EPI, int TM, int TN>
__global__ __launch_bounds__(512)
void gemm_nt(const bfraw* __restrict__ A, const bfraw* __restrict__ B,
             int N, int K,
             const float* __restrict__ bias,
             bfraw* __restrict__ outb, unsigned char* __restrict__ outf8,
             const float* __restrict__ u0a, const float* __restrict__ v0a,
             const float* __restrict__ su1, const float* __restrict__ sv1,
             const float* __restrict__ icb0, const float* __restrict__ icb1,
             float* __restrict__ z1f, float* __restrict__ z2pre)
{
  constexpr int MF = TM / 32;
  constexpr int NF = TN / 64;
  constexpr int LPB = TM / 64 + TN / 64;
  __shared__ bfraw lA[3][TM * 64];
  __shared__ bfraw lB[3][TN * 64];
  const int tid = threadIdx.x;
  const int w  = tid >> 6;
  const int l  = tid & 63;
  const int wr = w >> 2;
  const int wc = w & 3;
  const int bm = blockIdx.x;
  const int bn = blockIdx.y;
  const int lr = l & 15;
  const int q  = l >> 4;

  f32x4 acc[MF][NF] = {};
  const int nt = K >> 6;

  auto stage = [&](int buf, int k0){
    #pragma unroll
    for (int j = 0; j < TM / 64; ++j){
      const int c = j * 512 + tid;
      const int r = c >> 3;
      const int kc = (c & 7) ^ (r & 7);
      gload16(A + (size_t)(bm * TM + r) * K + k0 + kc * 8, &lA[buf][(size_t)(j * 512 + w * 64) * 8]);
    }
    #pragma unroll
    for (int j = 0; j < TN / 64; ++j){
      const int c = j * 512 + tid;
      const int r = c >> 3;
      const int kc = (c & 7) ^ (r & 7);
      gload16(B + (size_t)(bn * TN + r) * K + k0 + kc * 8, &lB[buf][(size_t)(j * 512 + w * 64) * 8]);
    }
  };

  stage(0, 0);
  stage(1, 64);
  for (int t = 0; t < nt; ++t){
    const int cur = t % 3;
    if (t == nt - 1) wait_vm<0>(); else wait_vm<LPB>();
    block_barrier();
    short8 aF[2][MF], bF[2][NF];
    #pragma unroll
    for (int kh = 0; kh < 2; ++kh){
      #pragma unroll
      for (int m = 0; m < MF; ++m){
        const int R = wr * (TM / 2) + m * 16 + lr;
        const int kch = (kh * 4 + q) ^ (lr & 7);
        aF[kh][m] = *reinterpret_cast<const short8*>(&lA[cur][(size_t)R * 64 + kch * 8]);
      }
      #pragma unroll
      for (int n = 0; n < NF; ++n){
        const int R = wc * (TN / 4) + n * 16 + lr;
        const int kch = (kh * 4 + q) ^ (lr & 7);
        bF[kh][n] = *reinterpret_cast<const short8*>(&lB[cur][(size_t)R * 64 + kch * 8]);
      }
    }
    if (t + 2 < nt) stage((t + 2) % 3, (t + 2) * 64);
    #pragma unroll
    for (int kh = 0; kh < 2; ++kh){
      #pragma unroll
      for (int m = 0; m < MF; ++m){
        #pragma unroll
        for (int n = 0; n < NF; ++n){
          acc[m][n] = __builtin_amdgcn_mfma_f32_16x16x32_bf16(aF[kh][m], bF[kh][n], acc[m][n], 0, 0, 0);
        }
      }
    }
  }

  #pragma unroll
  for (int m = 0; m < MF; ++m){
    #pragma unroll
    for (int n = 0; n < NF; ++n){
      #pragma unroll
      for (int r = 0; r < 4; ++r){
        const int row = bm * TM + wr * (TM / 2) + m * 16 + q * 4 + r;
        const int col = bn * TN + wc * (TN / 4) + n * 16 + lr;
        const float v = acc[m][n][r];
        if constexpr (EPI == 0){
          outf8[(size_t)row * N + col] = f2f8(v);
        } else if constexpr (EPI == 2){
          outf8[(size_t)row * N + col] = f2f8(tanhf(v + bias[col]));
        } else if constexpr (EPI == 4){
          if (col < 512){
            const float h = v - u0a[row] * su1[col] - v0a[row] * sv1[col] + bias[col];
            outb[(size_t)row * 512 + col] = f2b(tanhf(h));
          } else if (col < 576){
            z1f[(size_t)row * 64 + (col - 512)] = srelu(v + icb0[col - 512]);
          } else {
            z2pre[(size_t)row * 64 + (col - 576)] = v + icb1[col - 576];
          }
        }
      }
    }
  }
}

// ---------------- col-paired output GEMM, FP8 inputs, BK=128 (verified R12) ----------------
__global__ __launch_bounds__(512, 4)
void gemm_out(const unsigned char* __restrict__ hub8, const unsigned char* __restrict__ lm8,
              const unsigned char* __restrict__ h2b8, const unsigned char* __restrict__ w3f8,
              const bfraw* __restrict__ stateb, const float* __restrict__ b3,
              const float* __restrict__ u0a, const float* __restrict__ v0a,
              float* __restrict__ out)
{
  __shared__ unsigned char lA[128 * 128];    // 16KB
  __shared__ unsigned char lBlo[64 * 128];   // 8KB
  __shared__ unsigned char lBhi[64 * 128];   // 8KB
  const int tid = threadIdx.x;      // 512
  const int w  = tid >> 6;
  const int l  = tid & 63;
  const int wr = w >> 2;
  const int wc = w & 3;
  const int bm = blockIdx.x;        // 0..31
  const int bn = blockIdx.y;        // 0..15
  const int lr = l & 15;
  const int q  = l >> 4;

  const unsigned char* Au  = h2b8 + (size_t)(bm * 128) * 512;
  const unsigned char* Bwl = w3f8 + (size_t)(bn * 64) * 512;
  const unsigned char* Bwh = w3f8 + (size_t)(1024 + bn * 64) * 512;
  const unsigned char* Ah  = hub8 + (size_t)(bm * 128) * 1024;
  const unsigned char* Bl  = lm8  + (size_t)(bn * 64) * 1024;

  f32x4 acc2[4] = {};   // un lo
  f32x4 acc3[4] = {};   // un hi

  // ---------- phase 1: un combined (K=512, 4 tiles of BK=128) ----------
  for (int t = 0; t < 4; ++t){
    const int k0 = t * 128;
    #pragma unroll
    for (int j = 0; j < 2; ++j){
      const int c = j * 512 + tid;
      const int r = c >> 3;
      const int kc = (c & 7) ^ (r & 7);
      gload16(Au + (size_t)r * 512 + k0 + kc * 16, &lA[(size_t)(j * 512 + w * 64) * 16]);
    }
    {
      const int r = tid >> 3;
      const int kc = (tid & 7) ^ (r & 7);
      gload16(Bwl + (size_t)r * 512 + k0 + kc * 16, &lBlo[(size_t)(w * 64) * 16]);
      gload16(Bwh + (size_t)r * 512 + k0 + kc * 16, &lBhi[(size_t)(w * 64) * 16]);
    }
    __syncthreads();
    #pragma unroll
    for (int kh = 0; kh < 4; ++kh){
      const int ko = kh * 32 + q * 8;
      const int ch = (ko >> 4) ^ (lr & 7);
      const int bo = ko & 15;
      long long aF[4], bL, bH;
      #pragma unroll
      for (int m = 0; m < 4; ++m){
        const int R = wr * 64 + m * 16 + lr;
        aF[m] = *reinterpret_cast<const long long*>(&lA[(size_t)R * 128 + ch * 16 + bo]);
      }
      const int Rb = wc * 16 + lr;
      bL = *reinterpret_cast<const long long*>(&lBlo[(size_t)Rb * 128 + ch * 16 + bo]);
      bH = *reinterpret_cast<const long long*>(&lBhi[(size_t)Rb * 128 + ch * 16 + bo]);
      #pragma unroll
      for (int m = 0; m < 4; ++m){
        acc2[m] = __builtin_amdgcn_mfma_f32_16x16x32_fp8_fp8(aF[m], bL, acc2[m], 0, 0, 0);
        acc3[m] = __builtin_amdgcn_mfma_f32_16x16x32_fp8_fp8(aF[m], bH, acc3[m], 0, 0, 0);
      }
    }
    __syncthreads();
  }

  // ---------- write hi cols: dv + clamp(un_hi * (v - v0)) ----------
  #pragma unroll
  for (int m = 0; m < 4; ++m){
    #pragma unroll
    for (int r = 0; r < 4; ++r){
      const int row = bm * 128 + wr * 64 + m * 16 + q * 4 + r;
      const int c   = bn * 64 + wc * 16 + lr;
      const float un = acc3[m][r] + b3[1024 + c];
      const float u  = b2f(stateb[(size_t)row * 2048 + c]);
      const float vv = b2f(stateb[(size_t)row * 2048 + 1024 + c]);
      const float x  = vv - v0a[row];
      const float ux = un * x;
      const float cl = (ux < 10.0f && -10.0f < ux) ? ux : 0.0f;
      out[(size_t)row * 2049 + 1024 + c] = 0.2f * (u + 0.7f - 0.8f * vv) + cl;
    }
  }

  // ---------- phase 2: du (K=1024, 8 tiles of BK=128) ----------
  f32x4 acc1[4] = {};
  for (int t = 0; t < 8; ++t){
    const int k0 = t * 128;
    #pragma unroll
    for (int j = 0; j < 2; ++j){
      const int c = j * 512 + tid;
      const int r = c >> 3;
      const int kc = (c & 7) ^ (r & 7);
      gload16(Ah + (size_t)r * 1024 + k0 + kc * 16, &lA[(size_t)(j * 512 + w * 64) * 16]);
    }
    {
      const int r = tid >> 3;
      const int kc = (tid & 7) ^ (r & 7);
      gload16(Bl + (size_t)r * 1024 + k0 + kc * 16, &lBlo[(size_t)(w * 64) * 16]);
    }
    __syncthreads();
    #pragma unroll
    for (int kh = 0; kh < 4; ++kh){
      const int ko = kh * 32 + q * 8;
      const int ch = (ko >> 4) ^ (lr & 7);
      const int bo = ko & 15;
      long long aF[4], bL;
      #pragma unroll
      for (int m = 0; m < 4; ++m){
        const int R = wr * 64 + m * 16 + lr;
        aF[m] = *reinterpret_cast<const long long*>(&lA[(size_t)R * 128 + ch * 16 + bo]);
      }
      const int Rb = wc * 16 + lr;
      bL = *reinterpret_cast<const long long*>(&lBlo[(size_t)Rb * 128 + ch * 16 + bo]);
      #pragma unroll
      for (int m = 0; m < 4; ++m){
        acc1[m] = __builtin_amdgcn_mfma_f32_16x16x32_fp8_fp8(aF[m], bL, acc1[m], 0, 0, 0);
      }
    }
    __syncthreads();
  }

  // ---------- write lo cols: du + u - u^3/3 - v + 1 + clamp(un_lo * (u - u0)) ----------
  #pragma unroll
  for (int m = 0; m < 4; ++m){
    #pragma unroll
    for (int r = 0; r < 4; ++r){
      const int row = bm * 128 + wr * 64 + m * 16 + q * 4 + r;
      const int c   = bn * 64 + wc * 16 + lr;
      const float un = acc2[m][r] + b3[c];
      const float u  = b2f(stateb[(size_t)row * 2048 + c]);
      const float vv = b2f(stateb[(size_t)row * 2048 + 1024 + c]);
      const float x  = u - u0a[row];
      const float ux = un * x;
      const float cl = (ux < 10.0f && -10.0f < ux) ? ux : 0.0f;
      out[(size_t)row * 2049 + c] = acc1[m][r] + u - u * u * u * (1.0f / 3.0f) - vv + 1.0f + cl;
    }
  }
}

// ---------------- launch ----------------
extern "C" void kernel_launch(void* const* d_in, const int* in_sizes, int n_in,
                              void* d_out, int out_size, void* d_ws, size_t ws_size,
                              hipStream_t stream){
  (void)in_sizes; (void)n_in; (void)out_size; (void)ws_size;
  const float* state = (const float*)d_in[0];
  const float* tp    = (const float*)d_in[1];
  const float* P     = (const float*)d_in[2];
  const float* W1    = (const float*)d_in[3];
  const float* b1    = (const float*)d_in[4];
  const float* W2    = (const float*)d_in[5];
  const float* b2    = (const float*)d_in[6];
  const float* W3    = (const float*)d_in[7];
  const float* b3    = (const float*)d_in[8];
  const float* icW0  = (const float*)d_in[9];
  const float* icb0  = (const float*)d_in[10];
  const float* icW1  = (const float*)d_in[11];
  const float* icb1  = (const float*)d_in[12];
  const float* icW2  = (const float*)d_in[13];
  const float* icb2  = (const float*)d_in[14];
  const float* icU0  = (const float*)d_in[15];
  const float* icU1  = (const float*)d_in[16];
  float* out = (float*)d_out;
  char* ws = (char*)d_ws;

  bfraw* stateb = (bfraw*)(ws + OFF_STATEB);
  unsigned char* hub8 = (unsigned char*)(ws + OFF_HUB);
  bfraw* pt     = (bfraw*)(ws + OFF_PT);
  bfraw* pteig  = (bfraw*)(ws + OFF_PTEIG);
  unsigned char* lm8  = (unsigned char*)(ws + OFF_LM8);
  bfraw* w1zb   = (bfraw*)(ws + OFF_W1ZB);
  bfraw* w2b    = (bfraw*)(ws + OFF_W2B);
  unsigned char* w3f8 = (unsigned char*)(ws + OFF_W38);
  bfraw* h1b    = (bfraw*)(ws + OFF_H1B);
  unsigned char* h28  = (unsigned char*)(ws + OFF_H28);
  float* z1f    = (float*)(ws + OFF_Z1F);
  float* z2pre  = (float*)(ws + OFF_Z2PRE);
  float* spU0   = (float*)(ws + OFF_SPU0);
  float* spU1   = (float*)(ws + OFF_SPU1);
  float* z0     = (float*)(ws + OFF_Z0);
  float* su1    = (float*)(ws + OFF_SU1);
  float* sv1    = (float*)(ws + OFF_SV1);
  float* u0a    = (float*)(ws + OFF_U0);
  float* v0a    = (float*)(ws + OFF_V0);

  prep_all<<<dim3(8193), 256, 0, stream>>>(W1, icW0, icW1, W2, W3, P, tp,
      icU0, icU1, icb0, icb1, icb2, state,
      w1zb, w2b, w3f8, pt, pteig, su1, sv1, spU0, spU1, z0,
      stateb, hub8, u0a, v0a);

  // Lm = (eig*P)^T @ P   (bf16 in -> fp8 out; 1024x1024, K=1024)
  gemm_nt<0, 64, 64><<<dim3(16, 16), 512, 0, stream>>>(pteig, pt, 1024, 1024,
      nullptr, nullptr, lm8, nullptr, nullptr, nullptr, nullptr, nullptr, nullptr, nullptr, nullptr);
  // h1 = tanh(state@W1^T - u0*su1 - v0*sv1 + b1) -> bf16 ; z1 ; z2pre   (4096x640, K=2048)
  gemm_nt<4, 64, 128><<<dim3(64, 5), 512, 0, stream>>>(stateb, w1zb, 640, 2048,
      b1, h1b, nullptr, u0a, v0a, su1, sv1, icb0, icb1, z1f, z2pre);
  // h2 = tanh(h1 @ W2^T + b2) -> fp8   (4096x512, K=512)
  gemm_nt<2, 64, 128><<<dim3(64, 4), 512, 0, stream>>>(h1b, w2b, 512, 512,
      b2, nullptr, h28, nullptr, nullptr, nullptr, nullptr, nullptr, nullptr, nullptr, nullptr);
  // out[:, :2048] (col-paired dual-K fused GEMM, fp8 inputs)
  gemm_out<<<dim3(32, 16), 512, 0, stream>>>(hub8, lm8, h28, w3f8, stateb, b3, u0a, v0a, out);

  v2_kernel<<<dim3(4096), 256, 0, stream>>>(stateb, icW2, z1f, z2pre, spU0, spU1, z0, icb2, out);
}